// Round 2
// baseline (3663.491 us; speedup 1.0000x reference)
//
#include <hip/hip_runtime.h>
#include <hip/hip_bf16.h>
#include <cstdint>
#include <cstddef>

// Problem constants
#define N_NODE 100000
#define N_EDGE 1600000
#define N_REL  4
#define DIM    128
#define CHUNK  2048
#define NCH    ((N_NODE + CHUNK - 1) / CHUNK)   // 49

// Histogram tiling
#define CH_E   200000                            // edges per chunk
#define NCHUNK 8                                 // chunks per relation
#define TS     16384                             // node-tile size (64 KB LDS)
#define NTILE  7                                 // ceil(100000/16384)

// ---------------------------------------------------------------------------
// 1) Tiled LDS histogram: P[r][c][n] = #edges in chunk c of rel r hitting n.
//    No global atomics (k_count's 484us was 12.8M memory-side atomics @32B).
// ---------------------------------------------------------------------------
__global__ __launch_bounds__(256) void k_hist(const int* __restrict__ idx,
                                              int* __restrict__ P) {
    __shared__ int hist[TS];
    int c = blockIdx.x, t = blockIdx.y, r = blockIdx.z;
    for (int i = threadIdx.x; i < TS; i += 256) hist[i] = 0;
    __syncthreads();
    int n0 = t * TS;
    int e0 = c * CH_E;
    int e1 = min(e0 + CH_E, N_EDGE);
    const int* ip = idx + (size_t)r * N_EDGE;
    for (int e = e0 + threadIdx.x; e < e1; e += 256) {
        unsigned n = (unsigned)(ip[e] - n0);
        if (n < TS) atomicAdd(&hist[n], 1);       // LDS atomic - cheap
    }
    __syncthreads();
    int* Pp = P + ((size_t)r * NCHUNK + c) * N_NODE;
    for (int i = threadIdx.x; i < TS; i += 256) {
        int n = n0 + i;
        if (n < N_NODE) Pp[n] = hist[i];
    }
}

// 2) Reduce partials over chunks -> cnt_in (for scan) + rinv_in/out
__global__ void k_reduce_rinv(const int* __restrict__ Pd, const int* __restrict__ Ps,
                              int* __restrict__ cnt_in, float* __restrict__ rinv_in,
                              float* __restrict__ rinv_out) {
    int i = blockIdx.x * blockDim.x + threadIdx.x;   // r*N + n
    if (i >= N_REL * N_NODE) return;
    int r = i / N_NODE, n = i - r * N_NODE;
    int ci = 0, co = 0;
#pragma unroll
    for (int c = 0; c < NCHUNK; ++c) {
        ci += Pd[((size_t)r * NCHUNK + c) * N_NODE + n];
        co += Ps[((size_t)r * NCHUNK + c) * N_NODE + n];
    }
    cnt_in[i]   = ci;
    rinv_in[i]  = rsqrtf((float)max(ci, 1));
    rinv_out[i] = rsqrtf((float)max(co, 1));
}

// ---------------------------------------------------------------------------
// 3) CSR-by-dst row_ptr: chunk sums -> scan partials -> chunk scan
// ---------------------------------------------------------------------------
__global__ void k_chunk_sum(const int* __restrict__ cnt_in, int* __restrict__ partials) {
    int r = blockIdx.y, ch = blockIdx.x;
    __shared__ int sdata[256];
    int s = 0;
    for (int i = 0; i < CHUNK / 256; ++i) {
        int n = ch * CHUNK + i * 256 + threadIdx.x;
        if (n < N_NODE) s += cnt_in[r * N_NODE + n];
    }
    sdata[threadIdx.x] = s;
    __syncthreads();
    for (int off = 128; off > 0; off >>= 1) {
        if (threadIdx.x < off) sdata[threadIdx.x] += sdata[threadIdx.x + off];
        __syncthreads();
    }
    if (threadIdx.x == 0) partials[r * NCH + ch] = sdata[0];
}

__global__ void k_scan_partials(const int* __restrict__ partials,
                                int* __restrict__ chunk_base, int* __restrict__ row_ptr) {
    __shared__ int sp[N_REL * NCH];
    int t = threadIdx.x;
    if (t < N_REL * NCH) sp[t] = partials[t];
    __syncthreads();
    if (t == 0) {
        for (int r = 0; r < N_REL; ++r) {
            int run = 0;
            for (int ch = 0; ch < NCH; ++ch) {
                chunk_base[r * NCH + ch] = run;
                run += sp[r * NCH + ch];
            }
            row_ptr[r * (N_NODE + 1) + N_NODE] = N_EDGE;
        }
    }
}

__global__ void k_chunk_scan(const int* __restrict__ cnt_in,
                             const int* __restrict__ chunk_base, int* __restrict__ row_ptr) {
    int r = blockIdx.y, ch = blockIdx.x;
    __shared__ int tsum[256];
    int base_n = ch * CHUNK;
    int vals[8];
    int loc = 0;
    for (int i = 0; i < 8; ++i) {
        int n = base_n + threadIdx.x * 8 + i;
        vals[i] = (n < N_NODE) ? cnt_in[r * N_NODE + n] : 0;
        loc += vals[i];
    }
    tsum[threadIdx.x] = loc;
    __syncthreads();
    for (int off = 1; off < 256; off <<= 1) {     // Hillis-Steele inclusive scan
        int y = (threadIdx.x >= off) ? tsum[threadIdx.x - off] : 0;
        __syncthreads();
        tsum[threadIdx.x] += y;
        __syncthreads();
    }
    int pos = chunk_base[r * NCH + ch] + tsum[threadIdx.x] - loc;  // exclusive
    for (int i = 0; i < 8; ++i) {
        int n = base_n + threadIdx.x * 8 + i;
        if (n < N_NODE) { row_ptr[r * (N_NODE + 1) + n] = pos; pos += vals[i]; }
    }
}

// 4) base[r][c][n] = row_ptr[r][n] + sum_{c'<c} P[r][c'][n]
//    gives every (chunk, node) a disjoint CSR slot range -> scatter w/o
//    global atomics.
__global__ void k_base(const int* __restrict__ Pd, const int* __restrict__ row_ptr,
                       int* __restrict__ base) {
    int i = blockIdx.x * blockDim.x + threadIdx.x;
    if (i >= N_REL * N_NODE) return;
    int r = i / N_NODE, n = i - r * N_NODE;
    int run = row_ptr[r * (N_NODE + 1) + n];
#pragma unroll
    for (int c = 0; c < NCHUNK; ++c) {
        size_t o = ((size_t)r * NCHUNK + c) * N_NODE + n;
        base[o] = run;
        run += Pd[o];
    }
}

// 5) Scatter edges into CSR slots, LDS cursors only.
//    c_e = ew * rinv_out[src] * rinv_in[dst]  (valid for BOTH layers)
__global__ __launch_bounds__(256) void k_scatter2(const int* __restrict__ src,
                          const int* __restrict__ dst, const float* __restrict__ ew,
                          const float* __restrict__ rinv_out, const float* __restrict__ rinv_in,
                          const int* __restrict__ base,
                          int* __restrict__ src_s, float* __restrict__ c_s) {
    __shared__ int cur[TS];
    int c = blockIdx.x, t = blockIdx.y, r = blockIdx.z;
    int n0 = t * TS;
    const int* bp = base + ((size_t)r * NCHUNK + c) * N_NODE;
    for (int i = threadIdx.x; i < TS; i += 256) {
        int n = n0 + i;
        cur[i] = (n < N_NODE) ? bp[n] : 0;
    }
    __syncthreads();
    int e0 = c * CH_E;
    int e1 = min(e0 + CH_E, N_EDGE);
    size_t roff = (size_t)r * N_EDGE;
    for (int e = e0 + threadIdx.x; e < e1; e += 256) {
        unsigned d = (unsigned)(dst[roff + e] - n0);
        if (d < TS) {
            int s = src[roff + e];
            float cf = ew[roff + e] * rinv_out[r * N_NODE + s]
                                    * rinv_in[r * N_NODE + n0 + d];
            int pos = atomicAdd(&cur[d], 1);      // LDS atomic
            src_s[roff + pos] = s;
            c_s [roff + pos] = cf;
        }
    }
}

// ---------------------------------------------------------------------------
// 6) SpMM: tmp[n,:] = sum_{e in-edges of n} c_e * h[src_e,:]
//    one wave per dst node; lane owns 2 contiguous columns (float2).
//    4-deep unroll -> 4 outstanding 512B row gathers per wave (latency hiding).
// ---------------------------------------------------------------------------
__global__ void k_spmm(const int* __restrict__ row_ptr, const int* __restrict__ src_s,
                       const float* __restrict__ c_s, const float* __restrict__ h,
                       float* __restrict__ tmp, int r) {
    int wave = threadIdx.x >> 6;
    int lane = threadIdx.x & 63;
    int node = blockIdx.x * 4 + wave;
    if (node >= N_NODE) return;
    int k0 = row_ptr[r * (N_NODE + 1) + node];
    int k1 = row_ptr[r * (N_NODE + 1) + node + 1];
    const int*   ss = src_s + (size_t)r * N_EDGE;
    const float* cs = c_s  + (size_t)r * N_EDGE;
    const float2* h2 = (const float2*)h;
    float2 acc = make_float2(0.f, 0.f);
    int k = k0;
    for (; k + 3 < k1; k += 4) {
        int   s0 = ss[k],     s1 = ss[k + 1], s2 = ss[k + 2], s3 = ss[k + 3];
        float c0 = cs[k],     c1 = cs[k + 1], c2 = cs[k + 2], c3 = cs[k + 3];
        float2 v0 = h2[(size_t)s0 * 64 + lane];
        float2 v1 = h2[(size_t)s1 * 64 + lane];
        float2 v2 = h2[(size_t)s2 * 64 + lane];
        float2 v3 = h2[(size_t)s3 * 64 + lane];
        acc.x += c0 * v0.x; acc.y += c0 * v0.y;
        acc.x += c1 * v1.x; acc.y += c1 * v1.y;
        acc.x += c2 * v2.x; acc.y += c2 * v2.y;
        acc.x += c3 * v3.x; acc.y += c3 * v3.y;
    }
    for (; k < k1; ++k) {
        int s0 = ss[k]; float c0 = cs[k];
        float2 v0 = h2[(size_t)s0 * 64 + lane];
        acc.x += c0 * v0.x; acc.y += c0 * v0.y;
    }
    ((float2*)tmp)[(size_t)node * 64 + lane] = acc;
}

// ---------------------------------------------------------------------------
// 7) GEMM: out (op)= tmp[N,128] @ W[128,128]  (fp32 VALU; no fp32 MFMA on CDNA4)
//    mode 0: out = acc + sum_r b[r]; mode 1: out += acc; mode 2: relu(out+acc)
// ---------------------------------------------------------------------------
__global__ __launch_bounds__(256) void k_gemm(const float* __restrict__ A,
                                              const float* __restrict__ W,
                                              const float* __restrict__ b,
                                              float* __restrict__ out, int mode) {
    __shared__ float Wl[DIM * DIM];   // 64 KiB
    for (int i = 0; i < 64; ++i)
        Wl[threadIdx.x + i * 256] = W[threadIdx.x + i * 256];
    __syncthreads();

    int col  = threadIdx.x & 63;
    int rg   = threadIdx.x >> 6;
    int row0 = blockIdx.x * 64 + rg * 16;
    if (row0 >= N_NODE) return;   // N % 16 == 0 so rowgroups are full or empty

    float acc0[16], acc1[16];
#pragma unroll
    for (int i = 0; i < 16; ++i) { acc0[i] = 0.f; acc1[i] = 0.f; }

    for (int kb = 0; kb < DIM; kb += 4) {
        float4 a[16];
#pragma unroll
        for (int i = 0; i < 16; ++i)
            a[i] = *(const float4*)(A + (size_t)(row0 + i) * DIM + kb);
#pragma unroll
        for (int j = 0; j < 4; ++j) {
            float w0 = Wl[(kb + j) * DIM + col];
            float w1 = Wl[(kb + j) * DIM + col + 64];
#pragma unroll
            for (int i = 0; i < 16; ++i) {
                float av = (j == 0) ? a[i].x : (j == 1) ? a[i].y : (j == 2) ? a[i].z : a[i].w;
                acc0[i] += av * w0;
                acc1[i] += av * w1;
            }
        }
    }

    float bs0 = 0.f, bs1 = 0.f;
    if (mode == 0) {
#pragma unroll
        for (int r = 0; r < N_REL; ++r) {
            bs0 += b[r * DIM + col];
            bs1 += b[r * DIM + col + 64];
        }
    }
#pragma unroll
    for (int i = 0; i < 16; ++i) {
        size_t o = (size_t)(row0 + i) * DIM + col;
        if (mode == 0) {
            out[o]      = acc0[i] + bs0;
            out[o + 64] = acc1[i] + bs1;
        } else if (mode == 1) {
            out[o]      += acc0[i];
            out[o + 64] += acc1[i];
        } else {
            float v0 = out[o]      + acc0[i];
            float v1 = out[o + 64] + acc1[i];
            out[o]      = v0 > 0.f ? v0 : 0.f;
            out[o + 64] = v1 > 0.f ? v1 : 0.f;
        }
    }
}

// ---------------------------------------------------------------------------
extern "C" void kernel_launch(void* const* d_in, const int* in_sizes, int n_in,
                              void* d_out, int out_size, void* d_ws, size_t ws_size,
                              hipStream_t stream) {
    const float* x   = (const float*)d_in[0];
    const int*   src = (const int*)  d_in[1];
    const int*   dst = (const int*)  d_in[2];
    const float* ew  = (const float*)d_in[3];
    const float* W1  = (const float*)d_in[4];
    const float* b1  = (const float*)d_in[5];
    const float* W2  = (const float*)d_in[6];
    const float* b2  = (const float*)d_in[7];
    float* out = (float*)d_out;

    // Workspace carve-up (~160 MB). Pd/Ps/base alias tmp/h_mid: their
    // lifetimes end before spmm/gemm first write tmp/h_mid.
    char* p = (char*)d_ws;
    auto alloc = [&](size_t bytes) -> char* {
        char* q = p;
        p += (bytes + 255) & ~(size_t)255;
        return q;
    };
    const size_t RN = (size_t)N_REL * N_NODE;
    int*   cnt_in     = (int*)  alloc(RN * 4);
    float* rinv_out   = (float*)alloc(RN * 4);
    float* rinv_in    = (float*)alloc(RN * 4);
    int*   row_ptr    = (int*)  alloc((size_t)N_REL * (N_NODE + 1) * 4);
    int*   partials   = (int*)  alloc(N_REL * NCH * 4);
    int*   chunk_base = (int*)  alloc(N_REL * NCH * 4);
    int*   src_s      = (int*)  alloc((size_t)N_REL * N_EDGE * 4);
    float* c_s        = (float*)alloc((size_t)N_REL * N_EDGE * 4);
    float* tmp        = (float*)alloc((size_t)N_NODE * DIM * 4);   // 51.2 MB
    float* h_mid      = (float*)alloc((size_t)N_NODE * DIM * 4);   // 51.2 MB

    // Aliased preprocessing buffers (each 12.8 MB):
    int* Pd   = (int*)tmp;                            // dead before spmm
    int* Ps   = (int*)h_mid;                          // dead after k_reduce_rinv
    int* base = (int*)((char*)h_mid + (size_t)20 * 1024 * 1024); // dead before gemm

    dim3 gridH(NCHUNK, NTILE, N_REL);
    k_hist<<<gridH, 256, 0, stream>>>(dst, Pd);
    k_hist<<<gridH, 256, 0, stream>>>(src, Ps);
    k_reduce_rinv<<<(RN + 255) / 256, 256, 0, stream>>>(Pd, Ps, cnt_in, rinv_in, rinv_out);
    k_chunk_sum<<<dim3(NCH, N_REL), 256, 0, stream>>>(cnt_in, partials);
    k_scan_partials<<<1, 256, 0, stream>>>(partials, chunk_base, row_ptr);
    k_chunk_scan<<<dim3(NCH, N_REL), 256, 0, stream>>>(cnt_in, chunk_base, row_ptr);
    k_base<<<(RN + 255) / 256, 256, 0, stream>>>(Pd, row_ptr, base);
    k_scatter2<<<gridH, 256, 0, stream>>>(src, dst, ew, rinv_out, rinv_in, base, src_s, c_s);

    const int spmm_grid = (N_NODE + 3) / 4;
    const int gemm_grid = (N_NODE + 63) / 64;

    // layer 1: x -> h_mid
    for (int r = 0; r < N_REL; ++r) {
        k_spmm<<<spmm_grid, 256, 0, stream>>>(row_ptr, src_s, c_s, x, tmp, r);
        int mode = (r == 0) ? 0 : (r == N_REL - 1 ? 2 : 1);
        k_gemm<<<gemm_grid, 256, 0, stream>>>(tmp, W1 + (size_t)r * DIM * DIM, b1, h_mid, mode);
    }
    // layer 2: h_mid -> out
    for (int r = 0; r < N_REL; ++r) {
        k_spmm<<<spmm_grid, 256, 0, stream>>>(row_ptr, src_s, c_s, h_mid, tmp, r);
        int mode = (r == 0) ? 0 : (r == N_REL - 1 ? 2 : 1);
        k_gemm<<<gemm_grid, 256, 0, stream>>>(tmp, W2 + (size_t)r * DIM * DIM, b2, out, mode);
    }
}

// Round 3
// 3129.172 us; speedup vs baseline: 1.1708x; 1.1708x over previous
//
#include <hip/hip_runtime.h>
#include <hip/hip_bf16.h>
#include <cstdint>
#include <cstddef>

// Problem constants
#define N_NODE 100000
#define N_EDGE 1600000
#define N_REL  4
#define DIM    128
#define CHUNK  2048
#define NCH    ((N_NODE + CHUNK - 1) / CHUNK)   // 49

// Histogram tiling: 32x7x4 = 896 blocks (round 2's 224 was the bottleneck)
#define CH_E   50000                             // edges per chunk
#define NCHUNK 32                                // chunks per relation
#define TS     16384                             // node-tile size (64 KB LDS)
#define NTILE  7                                 // ceil(100000/16384)

// ---------------------------------------------------------------------------
// 1) Tiled LDS histogram: P[r][c][n] = #edges in chunk c of rel r hitting n.
//    No global atomics. 896 blocks ~ 3.5/CU against the 2-block/CU LDS limit.
// ---------------------------------------------------------------------------
__global__ __launch_bounds__(256) void k_hist(const int* __restrict__ idx,
                                              int* __restrict__ P) {
    __shared__ int hist[TS];
    int c = blockIdx.x, t = blockIdx.y, r = blockIdx.z;
    for (int i = threadIdx.x; i < TS; i += 256) hist[i] = 0;
    __syncthreads();
    int n0 = t * TS;
    int e0 = c * CH_E;
    int e1 = min(e0 + CH_E, N_EDGE);
    const int* ip = idx + (size_t)r * N_EDGE;
    for (int e = e0 + threadIdx.x; e < e1; e += 256) {
        unsigned n = (unsigned)(ip[e] - n0);
        if (n < TS) atomicAdd(&hist[n], 1);       // LDS atomic - cheap
    }
    __syncthreads();
    int* Pp = P + ((size_t)r * NCHUNK + c) * N_NODE;
    for (int i = threadIdx.x; i < TS; i += 256) {
        int n = n0 + i;
        if (n < N_NODE) Pp[n] = hist[i];
    }
}

// 2) Reduce partials over chunks -> cnt_in (for scan) + rinv_in/out
__global__ void k_reduce_rinv(const int* __restrict__ Pd, const int* __restrict__ Ps,
                              int* __restrict__ cnt_in, float* __restrict__ rinv_in,
                              float* __restrict__ rinv_out) {
    int i = blockIdx.x * blockDim.x + threadIdx.x;   // r*N + n
    if (i >= N_REL * N_NODE) return;
    int r = i / N_NODE, n = i - r * N_NODE;
    int ci = 0, co = 0;
#pragma unroll
    for (int c = 0; c < NCHUNK; ++c) {
        ci += Pd[((size_t)r * NCHUNK + c) * N_NODE + n];
        co += Ps[((size_t)r * NCHUNK + c) * N_NODE + n];
    }
    cnt_in[i]   = ci;
    rinv_in[i]  = rsqrtf((float)max(ci, 1));
    rinv_out[i] = rsqrtf((float)max(co, 1));
}

// ---------------------------------------------------------------------------
// 3) CSR-by-dst row_ptr: chunk sums -> scan partials -> chunk scan
// ---------------------------------------------------------------------------
__global__ void k_chunk_sum(const int* __restrict__ cnt_in, int* __restrict__ partials) {
    int r = blockIdx.y, ch = blockIdx.x;
    __shared__ int sdata[256];
    int s = 0;
    for (int i = 0; i < CHUNK / 256; ++i) {
        int n = ch * CHUNK + i * 256 + threadIdx.x;
        if (n < N_NODE) s += cnt_in[r * N_NODE + n];
    }
    sdata[threadIdx.x] = s;
    __syncthreads();
    for (int off = 128; off > 0; off >>= 1) {
        if (threadIdx.x < off) sdata[threadIdx.x] += sdata[threadIdx.x + off];
        __syncthreads();
    }
    if (threadIdx.x == 0) partials[r * NCH + ch] = sdata[0];
}

__global__ void k_scan_partials(const int* __restrict__ partials,
                                int* __restrict__ chunk_base, int* __restrict__ row_ptr) {
    __shared__ int sp[N_REL * NCH];
    int t = threadIdx.x;
    if (t < N_REL * NCH) sp[t] = partials[t];
    __syncthreads();
    if (t == 0) {
        for (int r = 0; r < N_REL; ++r) {
            int run = 0;
            for (int ch = 0; ch < NCH; ++ch) {
                chunk_base[r * NCH + ch] = run;
                run += sp[r * NCH + ch];
            }
            row_ptr[r * (N_NODE + 1) + N_NODE] = N_EDGE;
        }
    }
}

__global__ void k_chunk_scan(const int* __restrict__ cnt_in,
                             const int* __restrict__ chunk_base, int* __restrict__ row_ptr) {
    int r = blockIdx.y, ch = blockIdx.x;
    __shared__ int tsum[256];
    int base_n = ch * CHUNK;
    int vals[8];
    int loc = 0;
    for (int i = 0; i < 8; ++i) {
        int n = base_n + threadIdx.x * 8 + i;
        vals[i] = (n < N_NODE) ? cnt_in[r * N_NODE + n] : 0;
        loc += vals[i];
    }
    tsum[threadIdx.x] = loc;
    __syncthreads();
    for (int off = 1; off < 256; off <<= 1) {     // Hillis-Steele inclusive scan
        int y = (threadIdx.x >= off) ? tsum[threadIdx.x - off] : 0;
        __syncthreads();
        tsum[threadIdx.x] += y;
        __syncthreads();
    }
    int pos = chunk_base[r * NCH + ch] + tsum[threadIdx.x] - loc;  // exclusive
    for (int i = 0; i < 8; ++i) {
        int n = base_n + threadIdx.x * 8 + i;
        if (n < N_NODE) { row_ptr[r * (N_NODE + 1) + n] = pos; pos += vals[i]; }
    }
}

// 4) In-place: P[r][c][n] := row_ptr[r][n] + sum_{c'<c} P[r][c'][n]
//    gives every (chunk, node) a disjoint CSR slot range -> scatter w/o
//    global atomics. Per-(r,n) sequential, cross-thread independent.
__global__ void k_base(int* __restrict__ P, const int* __restrict__ row_ptr) {
    int i = blockIdx.x * blockDim.x + threadIdx.x;
    if (i >= N_REL * N_NODE) return;
    int r = i / N_NODE, n = i - r * N_NODE;
    int run = row_ptr[r * (N_NODE + 1) + n];
#pragma unroll
    for (int c = 0; c < NCHUNK; ++c) {
        size_t o = ((size_t)r * NCHUNK + c) * N_NODE + n;
        int p = P[o];
        P[o] = run;
        run += p;
    }
}

// 5) Scatter edges into CSR slots, LDS cursors only.
//    c_e = ew * rinv_out[src] * rinv_in[dst]  (valid for BOTH layers)
__global__ __launch_bounds__(256) void k_scatter2(const int* __restrict__ src,
                          const int* __restrict__ dst, const float* __restrict__ ew,
                          const float* __restrict__ rinv_out, const float* __restrict__ rinv_in,
                          const int* __restrict__ base,
                          int* __restrict__ src_s, float* __restrict__ c_s) {
    __shared__ int cur[TS];
    int c = blockIdx.x, t = blockIdx.y, r = blockIdx.z;
    int n0 = t * TS;
    const int* bp = base + ((size_t)r * NCHUNK + c) * N_NODE;
    for (int i = threadIdx.x; i < TS; i += 256) {
        int n = n0 + i;
        cur[i] = (n < N_NODE) ? bp[n] : 0;
    }
    __syncthreads();
    int e0 = c * CH_E;
    int e1 = min(e0 + CH_E, N_EDGE);
    size_t roff = (size_t)r * N_EDGE;
    for (int e = e0 + threadIdx.x; e < e1; e += 256) {
        unsigned d = (unsigned)(dst[roff + e] - n0);
        if (d < TS) {
            int s = src[roff + e];
            float cf = ew[roff + e] * rinv_out[r * N_NODE + s]
                                    * rinv_in[r * N_NODE + n0 + d];
            int pos = atomicAdd(&cur[d], 1);      // LDS atomic
            src_s[roff + pos] = s;
            c_s [roff + pos] = cf;
        }
    }
}

// ---------------------------------------------------------------------------
// 6) SpMM: tmp[n,:] = sum_{e in-edges of n} c_e * h[src_e,:]
//    one wave per dst node; lane owns 2 contiguous columns (float2).
//    4-deep unroll -> 4 outstanding 512B row gathers per wave (latency hiding).
// ---------------------------------------------------------------------------
__global__ void k_spmm(const int* __restrict__ row_ptr, const int* __restrict__ src_s,
                       const float* __restrict__ c_s, const float* __restrict__ h,
                       float* __restrict__ tmp, int r) {
    int wave = threadIdx.x >> 6;
    int lane = threadIdx.x & 63;
    int node = blockIdx.x * 4 + wave;
    if (node >= N_NODE) return;
    int k0 = row_ptr[r * (N_NODE + 1) + node];
    int k1 = row_ptr[r * (N_NODE + 1) + node + 1];
    const int*   ss = src_s + (size_t)r * N_EDGE;
    const float* cs = c_s  + (size_t)r * N_EDGE;
    const float2* h2 = (const float2*)h;
    float2 acc = make_float2(0.f, 0.f);
    int k = k0;
    for (; k + 3 < k1; k += 4) {
        int   s0 = ss[k],     s1 = ss[k + 1], s2 = ss[k + 2], s3 = ss[k + 3];
        float c0 = cs[k],     c1 = cs[k + 1], c2 = cs[k + 2], c3 = cs[k + 3];
        float2 v0 = h2[(size_t)s0 * 64 + lane];
        float2 v1 = h2[(size_t)s1 * 64 + lane];
        float2 v2 = h2[(size_t)s2 * 64 + lane];
        float2 v3 = h2[(size_t)s3 * 64 + lane];
        acc.x += c0 * v0.x; acc.y += c0 * v0.y;
        acc.x += c1 * v1.x; acc.y += c1 * v1.y;
        acc.x += c2 * v2.x; acc.y += c2 * v2.y;
        acc.x += c3 * v3.x; acc.y += c3 * v3.y;
    }
    for (; k < k1; ++k) {
        int s0 = ss[k]; float c0 = cs[k];
        float2 v0 = h2[(size_t)s0 * 64 + lane];
        acc.x += c0 * v0.x; acc.y += c0 * v0.y;
    }
    ((float2*)tmp)[(size_t)node * 64 + lane] = acc;
}

// ---------------------------------------------------------------------------
// 7) GEMM: out (op)= tmp[N,128] @ W[128,128]  (fp32 VALU; no fp32 MFMA on CDNA4)
//    mode 0: out = acc + sum_r b[r]; mode 1: out += acc; mode 2: relu(out+acc)
// ---------------------------------------------------------------------------
__global__ __launch_bounds__(256) void k_gemm(const float* __restrict__ A,
                                              const float* __restrict__ W,
                                              const float* __restrict__ b,
                                              float* __restrict__ out, int mode) {
    __shared__ float Wl[DIM * DIM];   // 64 KiB
    for (int i = 0; i < 64; ++i)
        Wl[threadIdx.x + i * 256] = W[threadIdx.x + i * 256];
    __syncthreads();

    int col  = threadIdx.x & 63;
    int rg   = threadIdx.x >> 6;
    int row0 = blockIdx.x * 64 + rg * 16;
    if (row0 >= N_NODE) return;   // N % 16 == 0 so rowgroups are full or empty

    float acc0[16], acc1[16];
#pragma unroll
    for (int i = 0; i < 16; ++i) { acc0[i] = 0.f; acc1[i] = 0.f; }

    for (int kb = 0; kb < DIM; kb += 4) {
        float4 a[16];
#pragma unroll
        for (int i = 0; i < 16; ++i)
            a[i] = *(const float4*)(A + (size_t)(row0 + i) * DIM + kb);
#pragma unroll
        for (int j = 0; j < 4; ++j) {
            float w0 = Wl[(kb + j) * DIM + col];
            float w1 = Wl[(kb + j) * DIM + col + 64];
#pragma unroll
            for (int i = 0; i < 16; ++i) {
                float av = (j == 0) ? a[i].x : (j == 1) ? a[i].y : (j == 2) ? a[i].z : a[i].w;
                acc0[i] += av * w0;
                acc1[i] += av * w1;
            }
        }
    }

    float bs0 = 0.f, bs1 = 0.f;
    if (mode == 0) {
#pragma unroll
        for (int r = 0; r < N_REL; ++r) {
            bs0 += b[r * DIM + col];
            bs1 += b[r * DIM + col + 64];
        }
    }
#pragma unroll
    for (int i = 0; i < 16; ++i) {
        size_t o = (size_t)(row0 + i) * DIM + col;
        if (mode == 0) {
            out[o]      = acc0[i] + bs0;
            out[o + 64] = acc1[i] + bs1;
        } else if (mode == 1) {
            out[o]      += acc0[i];
            out[o + 64] += acc1[i];
        } else {
            float v0 = out[o]      + acc0[i];
            float v1 = out[o + 64] + acc1[i];
            out[o]      = v0 > 0.f ? v0 : 0.f;
            out[o + 64] = v1 > 0.f ? v1 : 0.f;
        }
    }
}

// ---------------------------------------------------------------------------
extern "C" void kernel_launch(void* const* d_in, const int* in_sizes, int n_in,
                              void* d_out, int out_size, void* d_ws, size_t ws_size,
                              hipStream_t stream) {
    const float* x   = (const float*)d_in[0];
    const int*   src = (const int*)  d_in[1];
    const int*   dst = (const int*)  d_in[2];
    const float* ew  = (const float*)d_in[3];
    const float* W1  = (const float*)d_in[4];
    const float* b1  = (const float*)d_in[5];
    const float* W2  = (const float*)d_in[6];
    const float* b2  = (const float*)d_in[7];
    float* out = (float*)d_out;

    // Workspace carve-up (~160 MB, same footprint as round 2 = known safe).
    char* p = (char*)d_ws;
    auto alloc = [&](size_t bytes) -> char* {
        char* q = p;
        p += (bytes + 255) & ~(size_t)255;
        return q;
    };
    const size_t RN = (size_t)N_REL * N_NODE;
    int*   cnt_in     = (int*)  alloc(RN * 4);
    float* rinv_out   = (float*)alloc(RN * 4);
    float* rinv_in    = (float*)alloc(RN * 4);
    int*   row_ptr    = (int*)  alloc((size_t)N_REL * (N_NODE + 1) * 4);
    int*   partials   = (int*)  alloc(N_REL * NCH * 4);
    int*   chunk_base = (int*)  alloc(N_REL * NCH * 4);
    int*   src_s      = (int*)  alloc((size_t)N_REL * N_EDGE * 4);
    float* c_s        = (float*)alloc((size_t)N_REL * N_EDGE * 4);
    float* tmp        = (float*)alloc((size_t)N_NODE * DIM * 4);   // 51.2 MB
    float* h_mid      = (float*)alloc((size_t)N_NODE * DIM * 4);   // 51.2 MB

    // Aliased preprocessing buffers (each exactly 4*32*100000*4 = 51.2 MB):
    // Pd (dst partials -> in-place CSR bases) lives in tmp: dead before spmm.
    // Ps (src partials) lives in h_mid: dead after k_reduce_rinv, before gemm.
    int* Pd = (int*)tmp;
    int* Ps = (int*)h_mid;

    dim3 gridH(NCHUNK, NTILE, N_REL);   // 32 x 7 x 4 = 896 blocks
    k_hist<<<gridH, 256, 0, stream>>>(dst, Pd);
    k_hist<<<gridH, 256, 0, stream>>>(src, Ps);
    k_reduce_rinv<<<(RN + 255) / 256, 256, 0, stream>>>(Pd, Ps, cnt_in, rinv_in, rinv_out);
    k_chunk_sum<<<dim3(NCH, N_REL), 256, 0, stream>>>(cnt_in, partials);
    k_scan_partials<<<1, 256, 0, stream>>>(partials, chunk_base, row_ptr);
    k_chunk_scan<<<dim3(NCH, N_REL), 256, 0, stream>>>(cnt_in, chunk_base, row_ptr);
    k_base<<<(RN + 255) / 256, 256, 0, stream>>>(Pd, row_ptr);
    k_scatter2<<<gridH, 256, 0, stream>>>(src, dst, ew, rinv_out, rinv_in, Pd, src_s, c_s);

    const int spmm_grid = (N_NODE + 3) / 4;
    const int gemm_grid = (N_NODE + 63) / 64;

    // layer 1: x -> h_mid
    for (int r = 0; r < N_REL; ++r) {
        k_spmm<<<spmm_grid, 256, 0, stream>>>(row_ptr, src_s, c_s, x, tmp, r);
        int mode = (r == 0) ? 0 : (r == N_REL - 1 ? 2 : 1);
        k_gemm<<<gemm_grid, 256, 0, stream>>>(tmp, W1 + (size_t)r * DIM * DIM, b1, h_mid, mode);
    }
    // layer 2: h_mid -> out
    for (int r = 0; r < N_REL; ++r) {
        k_spmm<<<spmm_grid, 256, 0, stream>>>(row_ptr, src_s, c_s, h_mid, tmp, r);
        int mode = (r == 0) ? 0 : (r == N_REL - 1 ? 2 : 1);
        k_gemm<<<gemm_grid, 256, 0, stream>>>(tmp, W2 + (size_t)r * DIM * DIM, b2, out, mode);
    }
}

// Round 4
// 2972.502 us; speedup vs baseline: 1.2325x; 1.0527x over previous
//
#include <hip/hip_runtime.h>
#include <hip/hip_bf16.h>
#include <cstdint>
#include <cstddef>

// Problem constants
#define N_NODE 100000
#define N_EDGE 1600000
#define N_REL  4
#define DIM    128
#define CHUNK  2048
#define NCH    ((N_NODE + CHUNK - 1) / CHUNK)   // 49

// Histogram/scatter tiling: TS=8192 (32KB LDS) -> 5 blocks/CU (was 2 at 64KB).
#define CH_E   50000                             // edges per chunk
#define NCHUNK 32                                // chunks per relation
#define TS     8192                              // node-tile size (32 KB LDS)
#define NTILE  13                                // ceil(100000/8192)

// ---------------------------------------------------------------------------
// 1) Tiled LDS histogram: P[r][c][n] = #edges in chunk c of rel r hitting n.
// ---------------------------------------------------------------------------
__global__ __launch_bounds__(256) void k_hist(const int* __restrict__ idx,
                                              int* __restrict__ P) {
    __shared__ int hist[TS];
    int c = blockIdx.x, t = blockIdx.y, r = blockIdx.z;
    for (int i = threadIdx.x; i < TS; i += 256) hist[i] = 0;
    __syncthreads();
    int n0 = t * TS;
    int e0 = c * CH_E;
    int e1 = min(e0 + CH_E, N_EDGE);
    const int* ip = idx + (size_t)r * N_EDGE;
    for (int e = e0 + threadIdx.x; e < e1; e += 256) {
        unsigned n = (unsigned)(ip[e] - n0);
        if (n < TS) atomicAdd(&hist[n], 1);       // LDS atomic - cheap
    }
    __syncthreads();
    int* Pp = P + ((size_t)r * NCHUNK + c) * N_NODE;
    for (int i = threadIdx.x; i < TS; i += 256) {
        int n = n0 + i;
        if (n < N_NODE) Pp[n] = hist[i];
    }
}

// 2) Reduce partials over chunks -> cnt_in (for scan) + rinv_in/out
__global__ void k_reduce_rinv(const int* __restrict__ Pd, const int* __restrict__ Ps,
                              int* __restrict__ cnt_in, float* __restrict__ rinv_in,
                              float* __restrict__ rinv_out) {
    int i = blockIdx.x * blockDim.x + threadIdx.x;   // r*N + n
    if (i >= N_REL * N_NODE) return;
    int r = i / N_NODE, n = i - r * N_NODE;
    int ci = 0, co = 0;
#pragma unroll
    for (int c = 0; c < NCHUNK; ++c) {
        ci += Pd[((size_t)r * NCHUNK + c) * N_NODE + n];
        co += Ps[((size_t)r * NCHUNK + c) * N_NODE + n];
    }
    cnt_in[i]   = ci;
    rinv_in[i]  = rsqrtf((float)max(ci, 1));
    rinv_out[i] = rsqrtf((float)max(co, 1));
}

// ---------------------------------------------------------------------------
// 3) CSR-by-dst row_ptr: chunk sums -> scan partials -> chunk scan
// ---------------------------------------------------------------------------
__global__ void k_chunk_sum(const int* __restrict__ cnt_in, int* __restrict__ partials) {
    int r = blockIdx.y, ch = blockIdx.x;
    __shared__ int sdata[256];
    int s = 0;
    for (int i = 0; i < CHUNK / 256; ++i) {
        int n = ch * CHUNK + i * 256 + threadIdx.x;
        if (n < N_NODE) s += cnt_in[r * N_NODE + n];
    }
    sdata[threadIdx.x] = s;
    __syncthreads();
    for (int off = 128; off > 0; off >>= 1) {
        if (threadIdx.x < off) sdata[threadIdx.x] += sdata[threadIdx.x + off];
        __syncthreads();
    }
    if (threadIdx.x == 0) partials[r * NCH + ch] = sdata[0];
}

__global__ void k_scan_partials(const int* __restrict__ partials,
                                int* __restrict__ chunk_base, int* __restrict__ row_ptr) {
    __shared__ int sp[N_REL * NCH];
    int t = threadIdx.x;
    if (t < N_REL * NCH) sp[t] = partials[t];
    __syncthreads();
    if (t == 0) {
        for (int r = 0; r < N_REL; ++r) {
            int run = 0;
            for (int ch = 0; ch < NCH; ++ch) {
                chunk_base[r * NCH + ch] = run;
                run += sp[r * NCH + ch];
            }
            row_ptr[r * (N_NODE + 1) + N_NODE] = N_EDGE;
        }
    }
}

__global__ void k_chunk_scan(const int* __restrict__ cnt_in,
                             const int* __restrict__ chunk_base, int* __restrict__ row_ptr) {
    int r = blockIdx.y, ch = blockIdx.x;
    __shared__ int tsum[256];
    int base_n = ch * CHUNK;
    int vals[8];
    int loc = 0;
    for (int i = 0; i < 8; ++i) {
        int n = base_n + threadIdx.x * 8 + i;
        vals[i] = (n < N_NODE) ? cnt_in[r * N_NODE + n] : 0;
        loc += vals[i];
    }
    tsum[threadIdx.x] = loc;
    __syncthreads();
    for (int off = 1; off < 256; off <<= 1) {     // Hillis-Steele inclusive scan
        int y = (threadIdx.x >= off) ? tsum[threadIdx.x - off] : 0;
        __syncthreads();
        tsum[threadIdx.x] += y;
        __syncthreads();
    }
    int pos = chunk_base[r * NCH + ch] + tsum[threadIdx.x] - loc;  // exclusive
    for (int i = 0; i < 8; ++i) {
        int n = base_n + threadIdx.x * 8 + i;
        if (n < N_NODE) { row_ptr[r * (N_NODE + 1) + n] = pos; pos += vals[i]; }
    }
}

// 4) In-place: P[r][c][n] := row_ptr[r][n] + sum_{c'<c} P[r][c'][n]
__global__ void k_base(int* __restrict__ P, const int* __restrict__ row_ptr) {
    int i = blockIdx.x * blockDim.x + threadIdx.x;
    if (i >= N_REL * N_NODE) return;
    int r = i / N_NODE, n = i - r * N_NODE;
    int run = row_ptr[r * (N_NODE + 1) + n];
#pragma unroll
    for (int c = 0; c < NCHUNK; ++c) {
        size_t o = ((size_t)r * NCHUNK + c) * N_NODE + n;
        int p = P[o];
        P[o] = run;
        run += p;
    }
}

// 5) Scatter edges into CSR slots, LDS cursors only, single int2 payload
//    {src, bits(ew)}. No rinv math here (k_coef / spmm epilogue handle it).
__global__ __launch_bounds__(256) void k_scatter3(const int* __restrict__ src,
                          const int* __restrict__ dst, const float* __restrict__ ew,
                          const int* __restrict__ base, int2* __restrict__ pk_s) {
    __shared__ int cur[TS];
    int c = blockIdx.x, t = blockIdx.y, r = blockIdx.z;
    int n0 = t * TS;
    const int* bp = base + ((size_t)r * NCHUNK + c) * N_NODE;
    for (int i = threadIdx.x; i < TS; i += 256) {
        int n = n0 + i;
        cur[i] = (n < N_NODE) ? bp[n] : 0;
    }
    __syncthreads();
    int e0 = c * CH_E;
    int e1 = min(e0 + CH_E, N_EDGE);
    size_t roff = (size_t)r * N_EDGE;
    for (int e = e0 + threadIdx.x; e < e1; e += 256) {
        unsigned d = (unsigned)(dst[roff + e] - n0);
        if (d < TS) {
            int s = src[roff + e];
            float w = ew[roff + e];
            int pos = atomicAdd(&cur[d], 1);      // LDS atomic
            pk_s[roff + pos] = make_int2(s, __float_as_int(w));
        }
    }
}

// 6) Coalesced post-pass: pk.y = ew * rinv_out[r][src]  (rinv_out table is
//    1.6 MB -> L2-resident random gathers; everything else streams)
__global__ void k_coef(int2* __restrict__ pk_s, const float* __restrict__ rinv_out) {
    int e = blockIdx.x * blockDim.x + threadIdx.x;
    int r = blockIdx.y;
    if (e >= N_EDGE) return;
    size_t i = (size_t)r * N_EDGE + e;
    int2 pk = pk_s[i];
    float c = __int_as_float(pk.y) * rinv_out[r * N_NODE + pk.x];
    pk_s[i] = make_int2(pk.x, __float_as_int(c));
}

// ---------------------------------------------------------------------------
// 7) SpMM: tmp[n,:] = rinv_in[r][n] * sum_{e in-edges} c_e * h[src_e,:]
//    one wave per dst node; lane owns 2 contiguous columns (float2);
//    4-deep unroll; single 8B payload load per edge; rinv_in at epilogue.
// ---------------------------------------------------------------------------
__global__ void k_spmm(const int* __restrict__ row_ptr, const int2* __restrict__ pk_s,
                       const float* __restrict__ rinv_in, const float* __restrict__ h,
                       float* __restrict__ tmp, int r) {
    int wave = threadIdx.x >> 6;
    int lane = threadIdx.x & 63;
    int node = blockIdx.x * 4 + wave;
    if (node >= N_NODE) return;
    int k0 = row_ptr[r * (N_NODE + 1) + node];
    int k1 = row_ptr[r * (N_NODE + 1) + node + 1];
    const int2* pp = pk_s + (size_t)r * N_EDGE;
    const float2* h2 = (const float2*)h;
    float2 acc = make_float2(0.f, 0.f);
    int k = k0;
    for (; k + 3 < k1; k += 4) {
        int2 p0 = pp[k], p1 = pp[k + 1], p2 = pp[k + 2], p3 = pp[k + 3];
        float2 v0 = h2[(size_t)p0.x * 64 + lane];
        float2 v1 = h2[(size_t)p1.x * 64 + lane];
        float2 v2 = h2[(size_t)p2.x * 64 + lane];
        float2 v3 = h2[(size_t)p3.x * 64 + lane];
        float c0 = __int_as_float(p0.y), c1 = __int_as_float(p1.y);
        float c2 = __int_as_float(p2.y), c3 = __int_as_float(p3.y);
        acc.x += c0 * v0.x; acc.y += c0 * v0.y;
        acc.x += c1 * v1.x; acc.y += c1 * v1.y;
        acc.x += c2 * v2.x; acc.y += c2 * v2.y;
        acc.x += c3 * v3.x; acc.y += c3 * v3.y;
    }
    for (; k < k1; ++k) {
        int2 p0 = pp[k];
        float2 v0 = h2[(size_t)p0.x * 64 + lane];
        float c0 = __int_as_float(p0.y);
        acc.x += c0 * v0.x; acc.y += c0 * v0.y;
    }
    float ri = rinv_in[r * N_NODE + node];
    acc.x *= ri; acc.y *= ri;
    ((float2*)tmp)[(size_t)node * 64 + lane] = acc;
}

// ---------------------------------------------------------------------------
// 8) GEMM: out (op)= tmp[N,128] @ W[128,128]  (fp32 VALU; no fp32 MFMA on CDNA4)
//    mode 0: out = acc + sum_r b[r]; mode 1: out += acc; mode 2: relu(out+acc)
// ---------------------------------------------------------------------------
__global__ __launch_bounds__(256) void k_gemm(const float* __restrict__ A,
                                              const float* __restrict__ W,
                                              const float* __restrict__ b,
                                              float* __restrict__ out, int mode) {
    __shared__ float Wl[DIM * DIM];   // 64 KiB
    for (int i = 0; i < 64; ++i)
        Wl[threadIdx.x + i * 256] = W[threadIdx.x + i * 256];
    __syncthreads();

    int col  = threadIdx.x & 63;
    int rg   = threadIdx.x >> 6;
    int row0 = blockIdx.x * 64 + rg * 16;
    if (row0 >= N_NODE) return;   // N % 16 == 0 so rowgroups are full or empty

    float acc0[16], acc1[16];
#pragma unroll
    for (int i = 0; i < 16; ++i) { acc0[i] = 0.f; acc1[i] = 0.f; }

    for (int kb = 0; kb < DIM; kb += 4) {
        float4 a[16];
#pragma unroll
        for (int i = 0; i < 16; ++i)
            a[i] = *(const float4*)(A + (size_t)(row0 + i) * DIM + kb);
#pragma unroll
        for (int j = 0; j < 4; ++j) {
            float w0 = Wl[(kb + j) * DIM + col];
            float w1 = Wl[(kb + j) * DIM + col + 64];
#pragma unroll
            for (int i = 0; i < 16; ++i) {
                float av = (j == 0) ? a[i].x : (j == 1) ? a[i].y : (j == 2) ? a[i].z : a[i].w;
                acc0[i] += av * w0;
                acc1[i] += av * w1;
            }
        }
    }

    float bs0 = 0.f, bs1 = 0.f;
    if (mode == 0) {
#pragma unroll
        for (int r = 0; r < N_REL; ++r) {
            bs0 += b[r * DIM + col];
            bs1 += b[r * DIM + col + 64];
        }
    }
#pragma unroll
    for (int i = 0; i < 16; ++i) {
        size_t o = (size_t)(row0 + i) * DIM + col;
        if (mode == 0) {
            out[o]      = acc0[i] + bs0;
            out[o + 64] = acc1[i] + bs1;
        } else if (mode == 1) {
            out[o]      += acc0[i];
            out[o + 64] += acc1[i];
        } else {
            float v0 = out[o]      + acc0[i];
            float v1 = out[o + 64] + acc1[i];
            out[o]      = v0 > 0.f ? v0 : 0.f;
            out[o + 64] = v1 > 0.f ? v1 : 0.f;
        }
    }
}

// ---------------------------------------------------------------------------
extern "C" void kernel_launch(void* const* d_in, const int* in_sizes, int n_in,
                              void* d_out, int out_size, void* d_ws, size_t ws_size,
                              hipStream_t stream) {
    const float* x   = (const float*)d_in[0];
    const int*   src = (const int*)  d_in[1];
    const int*   dst = (const int*)  d_in[2];
    const float* ew  = (const float*)d_in[3];
    const float* W1  = (const float*)d_in[4];
    const float* b1  = (const float*)d_in[5];
    const float* W2  = (const float*)d_in[6];
    const float* b2  = (const float*)d_in[7];
    float* out = (float*)d_out;

    // Workspace carve-up (~160 MB, same footprint as rounds 2/3 = known safe).
    char* p = (char*)d_ws;
    auto alloc = [&](size_t bytes) -> char* {
        char* q = p;
        p += (bytes + 255) & ~(size_t)255;
        return q;
    };
    const size_t RN = (size_t)N_REL * N_NODE;
    int*   cnt_in     = (int*)  alloc(RN * 4);
    float* rinv_out   = (float*)alloc(RN * 4);
    float* rinv_in    = (float*)alloc(RN * 4);
    int*   row_ptr    = (int*)  alloc((size_t)N_REL * (N_NODE + 1) * 4);
    int*   partials   = (int*)  alloc(N_REL * NCH * 4);
    int*   chunk_base = (int*)  alloc(N_REL * NCH * 4);
    int2*  pk_s       = (int2*) alloc((size_t)N_REL * N_EDGE * 8);  // 51.2 MB
    float* tmp        = (float*)alloc((size_t)N_NODE * DIM * 4);    // 51.2 MB
    float* h_mid      = (float*)alloc((size_t)N_NODE * DIM * 4);    // 51.2 MB

    // Aliased preprocessing buffers (each exactly 4*32*100000*4 = 51.2 MB):
    // Pd (dst partials -> in-place CSR bases) lives in tmp: dead before spmm.
    // Ps (src partials) lives in h_mid: dead after k_reduce_rinv, before gemm.
    int* Pd = (int*)tmp;
    int* Ps = (int*)h_mid;

    dim3 gridH(NCHUNK, NTILE, N_REL);   // 32 x 13 x 4 = 1664 blocks
    k_hist<<<gridH, 256, 0, stream>>>(dst, Pd);
    k_hist<<<gridH, 256, 0, stream>>>(src, Ps);
    k_reduce_rinv<<<(RN + 255) / 256, 256, 0, stream>>>(Pd, Ps, cnt_in, rinv_in, rinv_out);
    k_chunk_sum<<<dim3(NCH, N_REL), 256, 0, stream>>>(cnt_in, partials);
    k_scan_partials<<<1, 256, 0, stream>>>(partials, chunk_base, row_ptr);
    k_chunk_scan<<<dim3(NCH, N_REL), 256, 0, stream>>>(cnt_in, chunk_base, row_ptr);
    k_base<<<(RN + 255) / 256, 256, 0, stream>>>(Pd, row_ptr);
    k_scatter3<<<gridH, 256, 0, stream>>>(src, dst, ew, Pd, pk_s);
    k_coef<<<dim3((N_EDGE + 255) / 256, N_REL), 256, 0, stream>>>(pk_s, rinv_out);

    const int spmm_grid = (N_NODE + 3) / 4;
    const int gemm_grid = (N_NODE + 63) / 64;

    // layer 1: x -> h_mid
    for (int r = 0; r < N_REL; ++r) {
        k_spmm<<<spmm_grid, 256, 0, stream>>>(row_ptr, pk_s, rinv_in, x, tmp, r);
        int mode = (r == 0) ? 0 : (r == N_REL - 1 ? 2 : 1);
        k_gemm<<<gemm_grid, 256, 0, stream>>>(tmp, W1 + (size_t)r * DIM * DIM, b1, h_mid, mode);
    }
    // layer 2: h_mid -> out
    for (int r = 0; r < N_REL; ++r) {
        k_spmm<<<spmm_grid, 256, 0, stream>>>(row_ptr, pk_s, rinv_in, h_mid, tmp, r);
        int mode = (r == 0) ? 0 : (r == N_REL - 1 ? 2 : 1);
        k_gemm<<<gemm_grid, 256, 0, stream>>>(tmp, W2 + (size_t)r * DIM * DIM, b2, out, mode);
    }
}

// Round 5
// 2309.475 us; speedup vs baseline: 1.5863x; 1.2871x over previous
//
#include <hip/hip_runtime.h>
#include <hip/hip_bf16.h>
#include <cstdint>
#include <cstddef>

// Problem constants
#define N_NODE 100000
#define N_EDGE 1600000
#define N_REL  4
#define DIM    128
#define CHUNK  2048
#define NCH    ((N_NODE + CHUNK - 1) / CHUNK)   // 49

// Histogram/scatter tiling: TS=8192 (32KB LDS) -> 5 blocks/CU.
#define CH_E   50000                             // edges per chunk (div by 4)
#define NCHUNK 32                                // chunks per relation
#define TS     8192                              // node-tile size (32 KB LDS)
#define NTILE  13                                // ceil(100000/8192)

__device__ inline unsigned short f2bf(float f) {
    __hip_bfloat16 b = __float2bfloat16(f);
    return *reinterpret_cast<unsigned short*>(&b);
}

// ---------------------------------------------------------------------------
// 1) Tiled LDS histogram, 4-edge unroll via int4 streaming loads.
// ---------------------------------------------------------------------------
__global__ __launch_bounds__(256) void k_hist(const int* __restrict__ idx,
                                              int* __restrict__ P) {
    __shared__ int hist[TS];
    int c = blockIdx.x, t = blockIdx.y, r = blockIdx.z;
    for (int i = threadIdx.x; i < TS; i += 256) hist[i] = 0;
    __syncthreads();
    int n0 = t * TS;
    int e0 = c * CH_E;
    const int* ip = idx + (size_t)r * N_EDGE;
    for (int e = e0 + threadIdx.x * 4; e < e0 + CH_E; e += 1024) {
        int4 d4 = *(const int4*)(ip + e);
        unsigned a0 = (unsigned)(d4.x - n0), a1 = (unsigned)(d4.y - n0);
        unsigned a2 = (unsigned)(d4.z - n0), a3 = (unsigned)(d4.w - n0);
        if (a0 < TS) atomicAdd(&hist[a0], 1);
        if (a1 < TS) atomicAdd(&hist[a1], 1);
        if (a2 < TS) atomicAdd(&hist[a2], 1);
        if (a3 < TS) atomicAdd(&hist[a3], 1);
    }
    __syncthreads();
    int* Pp = P + ((size_t)r * NCHUNK + c) * N_NODE;
    for (int i = threadIdx.x; i < TS; i += 256) {
        int n = n0 + i;
        if (n < N_NODE) Pp[n] = hist[i];
    }
}

// 2) Reduce partials over chunks -> cnt_in (for scan) + rinv_in/out
__global__ void k_reduce_rinv(const int* __restrict__ Pd, const int* __restrict__ Ps,
                              int* __restrict__ cnt_in, float* __restrict__ rinv_in,
                              float* __restrict__ rinv_out) {
    int i = blockIdx.x * blockDim.x + threadIdx.x;   // r*N + n
    if (i >= N_REL * N_NODE) return;
    int r = i / N_NODE, n = i - r * N_NODE;
    int ci = 0, co = 0;
#pragma unroll
    for (int c = 0; c < NCHUNK; ++c) {
        ci += Pd[((size_t)r * NCHUNK + c) * N_NODE + n];
        co += Ps[((size_t)r * NCHUNK + c) * N_NODE + n];
    }
    cnt_in[i]   = ci;
    rinv_in[i]  = rsqrtf((float)max(ci, 1));
    rinv_out[i] = rsqrtf((float)max(co, 1));
}

// ---------------------------------------------------------------------------
// 3) CSR-by-dst row_ptr: chunk sums -> scan partials -> chunk scan
// ---------------------------------------------------------------------------
__global__ void k_chunk_sum(const int* __restrict__ cnt_in, int* __restrict__ partials) {
    int r = blockIdx.y, ch = blockIdx.x;
    __shared__ int sdata[256];
    int s = 0;
    for (int i = 0; i < CHUNK / 256; ++i) {
        int n = ch * CHUNK + i * 256 + threadIdx.x;
        if (n < N_NODE) s += cnt_in[r * N_NODE + n];
    }
    sdata[threadIdx.x] = s;
    __syncthreads();
    for (int off = 128; off > 0; off >>= 1) {
        if (threadIdx.x < off) sdata[threadIdx.x] += sdata[threadIdx.x + off];
        __syncthreads();
    }
    if (threadIdx.x == 0) partials[r * NCH + ch] = sdata[0];
}

__global__ void k_scan_partials(const int* __restrict__ partials,
                                int* __restrict__ chunk_base, int* __restrict__ row_ptr) {
    __shared__ int sp[N_REL * NCH];
    int t = threadIdx.x;
    if (t < N_REL * NCH) sp[t] = partials[t];
    __syncthreads();
    if (t == 0) {
        for (int r = 0; r < N_REL; ++r) {
            int run = 0;
            for (int ch = 0; ch < NCH; ++ch) {
                chunk_base[r * NCH + ch] = run;
                run += sp[r * NCH + ch];
            }
            row_ptr[r * (N_NODE + 1) + N_NODE] = N_EDGE;
        }
    }
}

__global__ void k_chunk_scan(const int* __restrict__ cnt_in,
                             const int* __restrict__ chunk_base, int* __restrict__ row_ptr) {
    int r = blockIdx.y, ch = blockIdx.x;
    __shared__ int tsum[256];
    int base_n = ch * CHUNK;
    int vals[8];
    int loc = 0;
    for (int i = 0; i < 8; ++i) {
        int n = base_n + threadIdx.x * 8 + i;
        vals[i] = (n < N_NODE) ? cnt_in[r * N_NODE + n] : 0;
        loc += vals[i];
    }
    tsum[threadIdx.x] = loc;
    __syncthreads();
    for (int off = 1; off < 256; off <<= 1) {     // Hillis-Steele inclusive scan
        int y = (threadIdx.x >= off) ? tsum[threadIdx.x - off] : 0;
        __syncthreads();
        tsum[threadIdx.x] += y;
        __syncthreads();
    }
    int pos = chunk_base[r * NCH + ch] + tsum[threadIdx.x] - loc;  // exclusive
    for (int i = 0; i < 8; ++i) {
        int n = base_n + threadIdx.x * 8 + i;
        if (n < N_NODE) { row_ptr[r * (N_NODE + 1) + n] = pos; pos += vals[i]; }
    }
}

// 4) In-place: P[r][c][n] := row_ptr[r][n] + sum_{c'<c} P[r][c'][n]
__global__ void k_base(int* __restrict__ P, const int* __restrict__ row_ptr) {
    int i = blockIdx.x * blockDim.x + threadIdx.x;
    if (i >= N_REL * N_NODE) return;
    int r = i / N_NODE, n = i - r * N_NODE;
    int run = row_ptr[r * (N_NODE + 1) + n];
#pragma unroll
    for (int c = 0; c < NCHUNK; ++c) {
        size_t o = ((size_t)r * NCHUNK + c) * N_NODE + n;
        int p = P[o];
        P[o] = run;
        run += p;
    }
}

// 5) Scatter, 4-edge unroll, unconditional int4/float4 streams (dst,src,ew):
//    divergent body is just LDS-atomic + one 8B store.
__global__ __launch_bounds__(256) void k_scatter4(const int* __restrict__ src,
                          const int* __restrict__ dst, const float* __restrict__ ew,
                          const int* __restrict__ base, int2* __restrict__ pk_s) {
    __shared__ int cur[TS];
    int c = blockIdx.x, t = blockIdx.y, r = blockIdx.z;
    int n0 = t * TS;
    const int* bp = base + ((size_t)r * NCHUNK + c) * N_NODE;
    for (int i = threadIdx.x; i < TS; i += 256) {
        int n = n0 + i;
        cur[i] = (n < N_NODE) ? bp[n] : 0;
    }
    __syncthreads();
    int e0 = c * CH_E;
    size_t roff = (size_t)r * N_EDGE;
    for (int e = e0 + threadIdx.x * 4; e < e0 + CH_E; e += 1024) {
        int4   d4 = *(const int4*)  (dst + roff + e);
        int4   s4 = *(const int4*)  (src + roff + e);
        float4 w4 = *(const float4*)(ew  + roff + e);
        unsigned a; int pos;
        a = (unsigned)(d4.x - n0);
        if (a < TS) { pos = atomicAdd(&cur[a], 1); pk_s[roff + pos] = make_int2(s4.x, __float_as_int(w4.x)); }
        a = (unsigned)(d4.y - n0);
        if (a < TS) { pos = atomicAdd(&cur[a], 1); pk_s[roff + pos] = make_int2(s4.y, __float_as_int(w4.y)); }
        a = (unsigned)(d4.z - n0);
        if (a < TS) { pos = atomicAdd(&cur[a], 1); pk_s[roff + pos] = make_int2(s4.z, __float_as_int(w4.z)); }
        a = (unsigned)(d4.w - n0);
        if (a < TS) { pos = atomicAdd(&cur[a], 1); pk_s[roff + pos] = make_int2(s4.w, __float_as_int(w4.w)); }
    }
}

// 6) Coalesced post-pass: pk.y = ew * rinv_out[r][src]
__global__ void k_coef(int2* __restrict__ pk_s, const float* __restrict__ rinv_out) {
    int e = blockIdx.x * blockDim.x + threadIdx.x;
    int r = blockIdx.y;
    if (e >= N_EDGE) return;
    size_t i = (size_t)r * N_EDGE + e;
    int2 pk = pk_s[i];
    float c = __int_as_float(pk.y) * rinv_out[r * N_NODE + pk.x];
    pk_s[i] = make_int2(pk.x, __float_as_int(c));
}

// 7) fp32 -> bf16 matrix convert (4 elems/thread)
__global__ void k_cvt(const float* __restrict__ x, unsigned short* __restrict__ xb) {
    int i = blockIdx.x * blockDim.x + threadIdx.x;
    if (i >= N_NODE * DIM / 4) return;
    float4 v = ((const float4*)x)[i];
    ushort4 o;
    o.x = f2bf(v.x); o.y = f2bf(v.y); o.z = f2bf(v.z); o.w = f2bf(v.w);
    ((ushort4*)xb)[i] = o;
}

// ---------------------------------------------------------------------------
// 8) SpMM (bf16 gather): tmp[n,:] = rinv_in[r][n] * sum_e c_e * hb[src_e,:]
//    hb rows are 128 bf16 = 64 uint words; lane owns word `lane` (cols 2L,2L+1).
//    fp32 coefficients + fp32 accumulation.
// ---------------------------------------------------------------------------
__global__ void k_spmm(const int* __restrict__ row_ptr, const int2* __restrict__ pk_s,
                       const float* __restrict__ rinv_in, const unsigned* __restrict__ hb,
                       float* __restrict__ tmp, int r) {
    int wave = threadIdx.x >> 6;
    int lane = threadIdx.x & 63;
    int node = blockIdx.x * 4 + wave;
    if (node >= N_NODE) return;
    int k0 = row_ptr[r * (N_NODE + 1) + node];
    int k1 = row_ptr[r * (N_NODE + 1) + node + 1];
    const int2* pp = pk_s + (size_t)r * N_EDGE;
    float2 acc = make_float2(0.f, 0.f);
    int k = k0;
    for (; k + 3 < k1; k += 4) {
        int2 p0 = pp[k], p1 = pp[k + 1], p2 = pp[k + 2], p3 = pp[k + 3];
        unsigned u0 = hb[(size_t)p0.x * 64 + lane];
        unsigned u1 = hb[(size_t)p1.x * 64 + lane];
        unsigned u2 = hb[(size_t)p2.x * 64 + lane];
        unsigned u3 = hb[(size_t)p3.x * 64 + lane];
        float c0 = __int_as_float(p0.y), c1 = __int_as_float(p1.y);
        float c2 = __int_as_float(p2.y), c3 = __int_as_float(p3.y);
        acc.x += c0 * __uint_as_float(u0 << 16);
        acc.y += c0 * __uint_as_float(u0 & 0xffff0000u);
        acc.x += c1 * __uint_as_float(u1 << 16);
        acc.y += c1 * __uint_as_float(u1 & 0xffff0000u);
        acc.x += c2 * __uint_as_float(u2 << 16);
        acc.y += c2 * __uint_as_float(u2 & 0xffff0000u);
        acc.x += c3 * __uint_as_float(u3 << 16);
        acc.y += c3 * __uint_as_float(u3 & 0xffff0000u);
    }
    for (; k < k1; ++k) {
        int2 p0 = pp[k];
        unsigned u0 = hb[(size_t)p0.x * 64 + lane];
        float c0 = __int_as_float(p0.y);
        acc.x += c0 * __uint_as_float(u0 << 16);
        acc.y += c0 * __uint_as_float(u0 & 0xffff0000u);
    }
    float ri = rinv_in[r * N_NODE + node];
    acc.x *= ri; acc.y *= ri;
    ((float2*)tmp)[(size_t)node * 64 + lane] = acc;   // cols 2L,2L+1
}

// ---------------------------------------------------------------------------
// 9) GEMM: accum (op)= tmp[N,128] @ W[128,128]  (fp32 VALU)
//    mode 0: accum = acc + sum_r b[r]; mode 1: accum += acc;
//    mode 2: relu(accum+acc) -> outb (bf16) if outb != null, else accum (fp32)
// ---------------------------------------------------------------------------
__global__ __launch_bounds__(256) void k_gemm(const float* __restrict__ A,
                                              const float* __restrict__ W,
                                              const float* __restrict__ b,
                                              float* __restrict__ accum,
                                              unsigned short* __restrict__ outb,
                                              int mode) {
    __shared__ float Wl[DIM * DIM];   // 64 KiB
    for (int i = 0; i < 64; ++i)
        Wl[threadIdx.x + i * 256] = W[threadIdx.x + i * 256];
    __syncthreads();

    int col  = threadIdx.x & 63;
    int rg   = threadIdx.x >> 6;
    int row0 = blockIdx.x * 64 + rg * 16;
    if (row0 >= N_NODE) return;   // N % 16 == 0

    float acc0[16], acc1[16];
#pragma unroll
    for (int i = 0; i < 16; ++i) { acc0[i] = 0.f; acc1[i] = 0.f; }

    for (int kb = 0; kb < DIM; kb += 4) {
        float4 a[16];
#pragma unroll
        for (int i = 0; i < 16; ++i)
            a[i] = *(const float4*)(A + (size_t)(row0 + i) * DIM + kb);
#pragma unroll
        for (int j = 0; j < 4; ++j) {
            float w0 = Wl[(kb + j) * DIM + col];
            float w1 = Wl[(kb + j) * DIM + col + 64];
#pragma unroll
            for (int i = 0; i < 16; ++i) {
                float av = (j == 0) ? a[i].x : (j == 1) ? a[i].y : (j == 2) ? a[i].z : a[i].w;
                acc0[i] += av * w0;
                acc1[i] += av * w1;
            }
        }
    }

    float bs0 = 0.f, bs1 = 0.f;
    if (mode == 0) {
#pragma unroll
        for (int r = 0; r < N_REL; ++r) {
            bs0 += b[r * DIM + col];
            bs1 += b[r * DIM + col + 64];
        }
    }
#pragma unroll
    for (int i = 0; i < 16; ++i) {
        size_t o = (size_t)(row0 + i) * DIM + col;
        if (mode == 0) {
            accum[o]      = acc0[i] + bs0;
            accum[o + 64] = acc1[i] + bs1;
        } else if (mode == 1) {
            accum[o]      += acc0[i];
            accum[o + 64] += acc1[i];
        } else {
            float v0 = accum[o]      + acc0[i];
            float v1 = accum[o + 64] + acc1[i];
            v0 = v0 > 0.f ? v0 : 0.f;
            v1 = v1 > 0.f ? v1 : 0.f;
            if (outb) {
                outb[o]      = f2bf(v0);
                outb[o + 64] = f2bf(v1);
            } else {
                accum[o]      = v0;
                accum[o + 64] = v1;
            }
        }
    }
}

// ---------------------------------------------------------------------------
extern "C" void kernel_launch(void* const* d_in, const int* in_sizes, int n_in,
                              void* d_out, int out_size, void* d_ws, size_t ws_size,
                              hipStream_t stream) {
    const float* x   = (const float*)d_in[0];
    const int*   src = (const int*)  d_in[1];
    const int*   dst = (const int*)  d_in[2];
    const float* ew  = (const float*)d_in[3];
    const float* W1  = (const float*)d_in[4];
    const float* b1  = (const float*)d_in[5];
    const float* W2  = (const float*)d_in[6];
    const float* b2  = (const float*)d_in[7];
    float* out = (float*)d_out;   // also used as layer-1 fp32 accumulator

    // Workspace carve-up (~160 MB, same footprint as rounds 2-4 = known safe).
    char* p = (char*)d_ws;
    auto alloc = [&](size_t bytes) -> char* {
        char* q = p;
        p += (bytes + 255) & ~(size_t)255;
        return q;
    };
    const size_t RN = (size_t)N_REL * N_NODE;
    int*   cnt_in     = (int*)  alloc(RN * 4);
    float* rinv_out   = (float*)alloc(RN * 4);
    float* rinv_in    = (float*)alloc(RN * 4);
    int*   row_ptr    = (int*)  alloc((size_t)N_REL * (N_NODE + 1) * 4);
    int*   partials   = (int*)  alloc(N_REL * NCH * 4);
    int*   chunk_base = (int*)  alloc(N_REL * NCH * 4);
    int2*  pk_s       = (int2*) alloc((size_t)N_REL * N_EDGE * 8);  // 51.2 MB
    float* tmp        = (float*)alloc((size_t)N_NODE * DIM * 4);    // 51.2 MB
    char*  hreg       =         alloc((size_t)N_REL * NCHUNK * N_NODE * 4); // 51.2 MB

    // Aliases in the 51.2 MB regions:
    // Pd (dst partials -> in-place CSR bases) in tmp: dead before spmm.
    // Ps (src partials) in hreg: dead after k_reduce_rinv; then hreg splits:
    //   [0, 25.6MB)   h_mid_b : bf16 layer-1 output (written by gemm mode2)
    //   [25.6, 51.2)  xb      : bf16 copy of x (written by k_cvt)
    int* Pd = (int*)tmp;
    int* Ps = (int*)hreg;
    unsigned short* h_mid_b = (unsigned short*)hreg;
    unsigned short* xb      = (unsigned short*)(hreg + (size_t)N_NODE * DIM * 2);

    dim3 gridH(NCHUNK, NTILE, N_REL);   // 32 x 13 x 4 = 1664 blocks
    k_hist<<<gridH, 256, 0, stream>>>(dst, Pd);
    k_hist<<<gridH, 256, 0, stream>>>(src, Ps);
    k_reduce_rinv<<<(RN + 255) / 256, 256, 0, stream>>>(Pd, Ps, cnt_in, rinv_in, rinv_out);
    k_cvt<<<(N_NODE * DIM / 4 + 255) / 256, 256, 0, stream>>>(x, xb);  // after Ps is dead
    k_chunk_sum<<<dim3(NCH, N_REL), 256, 0, stream>>>(cnt_in, partials);
    k_scan_partials<<<1, 256, 0, stream>>>(partials, chunk_base, row_ptr);
    k_chunk_scan<<<dim3(NCH, N_REL), 256, 0, stream>>>(cnt_in, chunk_base, row_ptr);
    k_base<<<(RN + 255) / 256, 256, 0, stream>>>(Pd, row_ptr);
    k_scatter4<<<gridH, 256, 0, stream>>>(src, dst, ew, Pd, pk_s);
    k_coef<<<dim3((N_EDGE + 255) / 256, N_REL), 256, 0, stream>>>(pk_s, rinv_out);

    const int spmm_grid = (N_NODE + 3) / 4;
    const int gemm_grid = (N_NODE + 63) / 64;

    // layer 1: xb (bf16) -> h_mid_b (bf16); fp32 accumulation in d_out scratch
    for (int r = 0; r < N_REL; ++r) {
        k_spmm<<<spmm_grid, 256, 0, stream>>>(row_ptr, pk_s, rinv_in, (const unsigned*)xb, tmp, r);
        int mode = (r == 0) ? 0 : (r == N_REL - 1 ? 2 : 1);
        k_gemm<<<gemm_grid, 256, 0, stream>>>(tmp, W1 + (size_t)r * DIM * DIM, b1,
                                              out, (mode == 2) ? h_mid_b : (unsigned short*)nullptr, mode);
    }
    // layer 2: h_mid_b (bf16) -> out (fp32; overwritten from mode 0)
    for (int r = 0; r < N_REL; ++r) {
        k_spmm<<<spmm_grid, 256, 0, stream>>>(row_ptr, pk_s, rinv_in, (const unsigned*)h_mid_b, tmp, r);
        int mode = (r == 0) ? 0 : (r == N_REL - 1 ? 2 : 1);
        k_gemm<<<gemm_grid, 256, 0, stream>>>(tmp, W2 + (size_t)r * DIM * DIM, b2,
                                              out, (unsigned short*)nullptr, mode);
    }
}

// Round 6
// 1417.411 us; speedup vs baseline: 2.5846x; 1.6294x over previous
//
#include <hip/hip_runtime.h>
#include <hip/hip_bf16.h>
#include <cstdint>
#include <cstddef>

// Problem constants
#define N_NODE 100000
#define N_EDGE 1600000
#define N_REL  4
#define DIM    128
#define KDIM   512                               // N_REL * DIM stacked
#define HALF_N 50000
#define CHUNK  2048
#define NCH    ((N_NODE + CHUNK - 1) / CHUNK)   // 49

// Histogram/scatter tiling: TS=8192 (32KB LDS) -> 5 blocks/CU.
#define CH_E   50000                             // edges per chunk (div by 4)
#define NCHUNK 32                                // chunks per relation
#define TS     8192                              // node-tile size (32 KB LDS)
#define NTILE  13                                // ceil(100000/8192)

typedef __attribute__((ext_vector_type(8))) short bf16x8;   // 8 bf16 (4 VGPRs)
typedef __attribute__((ext_vector_type(4))) float f32x4;    // 4 fp32 acc

__device__ inline unsigned short f2bf(float f) {
    __hip_bfloat16 b = __float2bfloat16(f);
    return *reinterpret_cast<unsigned short*>(&b);
}

// ---------------------------------------------------------------------------
// 1) Tiled LDS histogram, 4-edge unroll via int4 streaming loads.
// ---------------------------------------------------------------------------
__global__ __launch_bounds__(256) void k_hist(const int* __restrict__ idx,
                                              int* __restrict__ P) {
    __shared__ int hist[TS];
    int c = blockIdx.x, t = blockIdx.y, r = blockIdx.z;
    for (int i = threadIdx.x; i < TS; i += 256) hist[i] = 0;
    __syncthreads();
    int n0 = t * TS;
    int e0 = c * CH_E;
    const int* ip = idx + (size_t)r * N_EDGE;
    for (int e = e0 + threadIdx.x * 4; e < e0 + CH_E; e += 1024) {
        int4 d4 = *(const int4*)(ip + e);
        unsigned a0 = (unsigned)(d4.x - n0), a1 = (unsigned)(d4.y - n0);
        unsigned a2 = (unsigned)(d4.z - n0), a3 = (unsigned)(d4.w - n0);
        if (a0 < TS) atomicAdd(&hist[a0], 1);
        if (a1 < TS) atomicAdd(&hist[a1], 1);
        if (a2 < TS) atomicAdd(&hist[a2], 1);
        if (a3 < TS) atomicAdd(&hist[a3], 1);
    }
    __syncthreads();
    int* Pp = P + ((size_t)r * NCHUNK + c) * N_NODE;
    for (int i = threadIdx.x; i < TS; i += 256) {
        int n = n0 + i;
        if (n < N_NODE) Pp[n] = hist[i];
    }
}

// 2) Reduce partials over chunks -> cnt_in (for scan) + rinv_in/out
__global__ void k_reduce_rinv(const int* __restrict__ Pd, const int* __restrict__ Ps,
                              int* __restrict__ cnt_in, float* __restrict__ rinv_in,
                              float* __restrict__ rinv_out) {
    int i = blockIdx.x * blockDim.x + threadIdx.x;   // r*N + n
    if (i >= N_REL * N_NODE) return;
    int r = i / N_NODE, n = i - r * N_NODE;
    int ci = 0, co = 0;
#pragma unroll
    for (int c = 0; c < NCHUNK; ++c) {
        ci += Pd[((size_t)r * NCHUNK + c) * N_NODE + n];
        co += Ps[((size_t)r * NCHUNK + c) * N_NODE + n];
    }
    cnt_in[i]   = ci;
    rinv_in[i]  = rsqrtf((float)max(ci, 1));
    rinv_out[i] = rsqrtf((float)max(co, 1));
}

// ---------------------------------------------------------------------------
// 3) CSR-by-dst row_ptr: chunk sums -> scan partials -> chunk scan
// ---------------------------------------------------------------------------
__global__ void k_chunk_sum(const int* __restrict__ cnt_in, int* __restrict__ partials) {
    int r = blockIdx.y, ch = blockIdx.x;
    __shared__ int sdata[256];
    int s = 0;
    for (int i = 0; i < CHUNK / 256; ++i) {
        int n = ch * CHUNK + i * 256 + threadIdx.x;
        if (n < N_NODE) s += cnt_in[r * N_NODE + n];
    }
    sdata[threadIdx.x] = s;
    __syncthreads();
    for (int off = 128; off > 0; off >>= 1) {
        if (threadIdx.x < off) sdata[threadIdx.x] += sdata[threadIdx.x + off];
        __syncthreads();
    }
    if (threadIdx.x == 0) partials[r * NCH + ch] = sdata[0];
}

__global__ void k_scan_partials(const int* __restrict__ partials,
                                int* __restrict__ chunk_base, int* __restrict__ row_ptr) {
    __shared__ int sp[N_REL * NCH];
    int t = threadIdx.x;
    if (t < N_REL * NCH) sp[t] = partials[t];
    __syncthreads();
    if (t == 0) {
        for (int r = 0; r < N_REL; ++r) {
            int run = 0;
            for (int ch = 0; ch < NCH; ++ch) {
                chunk_base[r * NCH + ch] = run;
                run += sp[r * NCH + ch];
            }
            row_ptr[r * (N_NODE + 1) + N_NODE] = N_EDGE;
        }
    }
}

__global__ void k_chunk_scan(const int* __restrict__ cnt_in,
                             const int* __restrict__ chunk_base, int* __restrict__ row_ptr) {
    int r = blockIdx.y, ch = blockIdx.x;
    __shared__ int tsum[256];
    int base_n = ch * CHUNK;
    int vals[8];
    int loc = 0;
    for (int i = 0; i < 8; ++i) {
        int n = base_n + threadIdx.x * 8 + i;
        vals[i] = (n < N_NODE) ? cnt_in[r * N_NODE + n] : 0;
        loc += vals[i];
    }
    tsum[threadIdx.x] = loc;
    __syncthreads();
    for (int off = 1; off < 256; off <<= 1) {     // Hillis-Steele inclusive scan
        int y = (threadIdx.x >= off) ? tsum[threadIdx.x - off] : 0;
        __syncthreads();
        tsum[threadIdx.x] += y;
        __syncthreads();
    }
    int pos = chunk_base[r * NCH + ch] + tsum[threadIdx.x] - loc;  // exclusive
    for (int i = 0; i < 8; ++i) {
        int n = base_n + threadIdx.x * 8 + i;
        if (n < N_NODE) { row_ptr[r * (N_NODE + 1) + n] = pos; pos += vals[i]; }
    }
}

// 4) In-place: P[r][c][n] := row_ptr[r][n] + sum_{c'<c} P[r][c'][n]
__global__ void k_base(int* __restrict__ P, const int* __restrict__ row_ptr) {
    int i = blockIdx.x * blockDim.x + threadIdx.x;
    if (i >= N_REL * N_NODE) return;
    int r = i / N_NODE, n = i - r * N_NODE;
    int run = row_ptr[r * (N_NODE + 1) + n];
#pragma unroll
    for (int c = 0; c < NCHUNK; ++c) {
        size_t o = ((size_t)r * NCHUNK + c) * N_NODE + n;
        int p = P[o];
        P[o] = run;
        run += p;
    }
}

// 5) Scatter, 4-edge unroll, unconditional int4/float4 streams.
__global__ __launch_bounds__(256) void k_scatter4(const int* __restrict__ src,
                          const int* __restrict__ dst, const float* __restrict__ ew,
                          const int* __restrict__ base, int2* __restrict__ pk_s) {
    __shared__ int cur[TS];
    int c = blockIdx.x, t = blockIdx.y, r = blockIdx.z;
    int n0 = t * TS;
    const int* bp = base + ((size_t)r * NCHUNK + c) * N_NODE;
    for (int i = threadIdx.x; i < TS; i += 256) {
        int n = n0 + i;
        cur[i] = (n < N_NODE) ? bp[n] : 0;
    }
    __syncthreads();
    int e0 = c * CH_E;
    size_t roff = (size_t)r * N_EDGE;
    for (int e = e0 + threadIdx.x * 4; e < e0 + CH_E; e += 1024) {
        int4   d4 = *(const int4*)  (dst + roff + e);
        int4   s4 = *(const int4*)  (src + roff + e);
        float4 w4 = *(const float4*)(ew  + roff + e);
        unsigned a; int pos;
        a = (unsigned)(d4.x - n0);
        if (a < TS) { pos = atomicAdd(&cur[a], 1); pk_s[roff + pos] = make_int2(s4.x, __float_as_int(w4.x)); }
        a = (unsigned)(d4.y - n0);
        if (a < TS) { pos = atomicAdd(&cur[a], 1); pk_s[roff + pos] = make_int2(s4.y, __float_as_int(w4.y)); }
        a = (unsigned)(d4.z - n0);
        if (a < TS) { pos = atomicAdd(&cur[a], 1); pk_s[roff + pos] = make_int2(s4.z, __float_as_int(w4.z)); }
        a = (unsigned)(d4.w - n0);
        if (a < TS) { pos = atomicAdd(&cur[a], 1); pk_s[roff + pos] = make_int2(s4.w, __float_as_int(w4.w)); }
    }
}

// 6) Coalesced post-pass: pk.y = ew * rinv_out[r][src]
__global__ void k_coef(int2* __restrict__ pk_s, const float* __restrict__ rinv_out) {
    int e = blockIdx.x * blockDim.x + threadIdx.x;
    int r = blockIdx.y;
    if (e >= N_EDGE) return;
    size_t i = (size_t)r * N_EDGE + e;
    int2 pk = pk_s[i];
    float c = __int_as_float(pk.y) * rinv_out[r * N_NODE + pk.x];
    pk_s[i] = make_int2(pk.x, __float_as_int(c));
}

// 7a) fp32 -> bf16 matrix convert (4 elems/thread)
__global__ void k_cvt(const float* __restrict__ x, unsigned short* __restrict__ xb) {
    int i = blockIdx.x * blockDim.x + threadIdx.x;
    if (i >= N_NODE * DIM / 4) return;
    float4 v = ((const float4*)x)[i];
    ushort4 o;
    o.x = f2bf(v.x); o.y = f2bf(v.y); o.z = f2bf(v.z); o.w = f2bf(v.w);
    ((ushort4*)xb)[i] = o;
}

// 7b) W [512][128] fp32 -> WT [128][512] bf16 (transpose for B-frag loads)
__global__ void k_cvt_w(const float* __restrict__ W, unsigned short* __restrict__ WT) {
    int i = blockIdx.x * blockDim.x + threadIdx.x;
    if (i >= KDIM * DIM) return;
    int k = i >> 7, j = i & 127;
    WT[(size_t)j * KDIM + k] = f2bf(W[i]);
}

// ---------------------------------------------------------------------------
// 8) Fused SpMM (all 4 relations): T[nl, r*128:+128] = rinv_in*sum c_e*hb[src]
//    One wave per node; lane owns dword `lane` of each 256B bf16 row.
//    Output row = 512 bf16 (stacked relations) ready for the K=512 GEMM.
// ---------------------------------------------------------------------------
__global__ void k_spmm4(const int* __restrict__ row_ptr, const int2* __restrict__ pk_s,
                        const float* __restrict__ rinv_in, const unsigned* __restrict__ hb,
                        unsigned* __restrict__ Tb, int node0) {
    int wave = threadIdx.x >> 6;
    int lane = threadIdx.x & 63;
    int nl   = blockIdx.x * 4 + wave;     // local row within half (grid exact)
    int node = node0 + nl;
    unsigned outv[N_REL];
#pragma unroll
    for (int r = 0; r < N_REL; ++r) {
        int k0 = row_ptr[r * (N_NODE + 1) + node];
        int k1 = row_ptr[r * (N_NODE + 1) + node + 1];
        const int2* pp = pk_s + (size_t)r * N_EDGE;
        float2 acc = make_float2(0.f, 0.f);
        int k = k0;
        for (; k + 3 < k1; k += 4) {
            int2 p0 = pp[k], p1 = pp[k + 1], p2 = pp[k + 2], p3 = pp[k + 3];
            unsigned u0 = hb[(size_t)p0.x * 64 + lane];
            unsigned u1 = hb[(size_t)p1.x * 64 + lane];
            unsigned u2 = hb[(size_t)p2.x * 64 + lane];
            unsigned u3 = hb[(size_t)p3.x * 64 + lane];
            float c0 = __int_as_float(p0.y), c1 = __int_as_float(p1.y);
            float c2 = __int_as_float(p2.y), c3 = __int_as_float(p3.y);
            acc.x += c0 * __uint_as_float(u0 << 16);
            acc.y += c0 * __uint_as_float(u0 & 0xffff0000u);
            acc.x += c1 * __uint_as_float(u1 << 16);
            acc.y += c1 * __uint_as_float(u1 & 0xffff0000u);
            acc.x += c2 * __uint_as_float(u2 << 16);
            acc.y += c2 * __uint_as_float(u2 & 0xffff0000u);
            acc.x += c3 * __uint_as_float(u3 << 16);
            acc.y += c3 * __uint_as_float(u3 & 0xffff0000u);
        }
        for (; k < k1; ++k) {
            int2 p0 = pp[k];
            unsigned u0 = hb[(size_t)p0.x * 64 + lane];
            float c0 = __int_as_float(p0.y);
            acc.x += c0 * __uint_as_float(u0 << 16);
            acc.y += c0 * __uint_as_float(u0 & 0xffff0000u);
        }
        float ri = rinv_in[r * N_NODE + node];
        acc.x *= ri; acc.y *= ri;
        outv[r] = ((unsigned)f2bf(acc.y) << 16) | (unsigned)f2bf(acc.x);
    }
#pragma unroll
    for (int r = 0; r < N_REL; ++r)
        Tb[(size_t)nl * 256 + r * 64 + lane] = outv[r];
}

// ---------------------------------------------------------------------------
// 9) MFMA GEMM: out[HALF_N,128] = relu(T[HALF_N,512] @ Wcat[512,128] + bias_sum)
//    mfma_f32_16x16x32_bf16; A-frag: m=lane&15, k=(lane>>4)*8+j (16B contig in T);
//    B-frag: n=lane&15, k=(lane>>4)*8+j (16B contig in WT[128][512]);
//    C/D: col=lane&15, row=(lane>>4)*4+reg (verified layouts).
//    Block 256 = 4 waves; wave = 16 rows x 128 cols = 8 acc tiles. No LDS:
//    WT (128KB) is L2-resident and shared by all blocks.
// ---------------------------------------------------------------------------
__global__ __launch_bounds__(256) void k_gemm(const unsigned short* __restrict__ Tb,
                                              const unsigned short* __restrict__ WT,
                                              const float* __restrict__ b,
                                              float* __restrict__ outf,
                                              unsigned short* __restrict__ outb,
                                              int node0) {
    int lane = threadIdx.x & 63;
    int wv   = threadIdx.x >> 6;
    int row0 = blockIdx.x * 64 + wv * 16;
    if (row0 >= HALF_N) return;            // HALF_N % 16 == 0: full-or-empty
    int m  = lane & 15;
    int kg = lane >> 4;

    f32x4 acc[8];
#pragma unroll
    for (int t = 0; t < 8; ++t) acc[t] = (f32x4){0.f, 0.f, 0.f, 0.f};

    const unsigned short* arow = Tb + (size_t)(row0 + m) * KDIM + kg * 8;
    for (int k0 = 0; k0 < KDIM; k0 += 32) {
        bf16x8 af = *(const bf16x8*)(arow + k0);
#pragma unroll
        for (int t = 0; t < 8; ++t) {
            bf16x8 bf = *(const bf16x8*)(WT + (size_t)(t * 16 + m) * KDIM + k0 + kg * 8);
            acc[t] = __builtin_amdgcn_mfma_f32_16x16x32_bf16(af, bf, acc[t], 0, 0, 0);
        }
    }

    int rbase = row0 + kg * 4;
#pragma unroll
    for (int t = 0; t < 8; ++t) {
        int col = t * 16 + m;
        float bs = b[col] + b[DIM + col] + b[2 * DIM + col] + b[3 * DIM + col];
#pragma unroll
        for (int rg = 0; rg < 4; ++rg) {
            float v = acc[t][rg] + bs;
            v = v > 0.f ? v : 0.f;         // relu in BOTH layers per reference
            size_t o = (size_t)(node0 + rbase + rg) * DIM + col;
            if (outb) outb[o] = f2bf(v);
            else      outf[o] = v;
        }
    }
}

// ---------------------------------------------------------------------------
extern "C" void kernel_launch(void* const* d_in, const int* in_sizes, int n_in,
                              void* d_out, int out_size, void* d_ws, size_t ws_size,
                              hipStream_t stream) {
    const float* x   = (const float*)d_in[0];
    const int*   src = (const int*)  d_in[1];
    const int*   dst = (const int*)  d_in[2];
    const float* ew  = (const float*)d_in[3];
    const float* W1  = (const float*)d_in[4];
    const float* b1  = (const float*)d_in[5];
    const float* W2  = (const float*)d_in[6];
    const float* b2  = (const float*)d_in[7];
    float* out = (float*)d_out;

    // Workspace carve-up (~162 MB, same proven footprint).
    char* p = (char*)d_ws;
    auto alloc = [&](size_t bytes) -> char* {
        char* q = p;
        p += (bytes + 255) & ~(size_t)255;
        return q;
    };
    const size_t RN = (size_t)N_REL * N_NODE;
    int*   cnt_in     = (int*)  alloc(RN * 4);
    float* rinv_out   = (float*)alloc(RN * 4);
    float* rinv_in    = (float*)alloc(RN * 4);
    int*   row_ptr    = (int*)  alloc((size_t)N_REL * (N_NODE + 1) * 4);
    int*   partials   = (int*)  alloc(N_REL * NCH * 4);
    int*   chunk_base = (int*)  alloc(N_REL * NCH * 4);
    unsigned short* WT1b = (unsigned short*)alloc((size_t)KDIM * DIM * 2);  // 128KB
    unsigned short* WT2b = (unsigned short*)alloc((size_t)KDIM * DIM * 2);  // 128KB
    int2*  pk_s       = (int2*) alloc((size_t)N_REL * N_EDGE * 8);          // 51.2 MB
    char*  Treg       =         alloc((size_t)HALF_N * KDIM * 2);           // 51.2 MB
    char*  hreg       =         alloc((size_t)N_REL * NCHUNK * N_NODE * 4); // 51.2 MB

    // Aliases:
    // Pd (dst partials -> CSR bases) in Treg: dead after k_scatter4, before spmm.
    // Ps (src partials) in hreg: dead after k_reduce_rinv; then hreg splits:
    //   [0, 25.6MB)   h_mid_b : bf16 layer-1 output
    //   [25.6, 51.2)  xb      : bf16 copy of x
    int* Pd = (int*)Treg;
    int* Ps = (int*)hreg;
    unsigned short* h_mid_b = (unsigned short*)hreg;
    unsigned short* xb      = (unsigned short*)(hreg + (size_t)N_NODE * DIM * 2);
    unsigned short* Tb      = (unsigned short*)Treg;

    dim3 gridH(NCHUNK, NTILE, N_REL);   // 32 x 13 x 4 = 1664 blocks
    k_hist<<<gridH, 256, 0, stream>>>(dst, Pd);
    k_hist<<<gridH, 256, 0, stream>>>(src, Ps);
    k_reduce_rinv<<<(RN + 255) / 256, 256, 0, stream>>>(Pd, Ps, cnt_in, rinv_in, rinv_out);
    k_cvt<<<(N_NODE * DIM / 4 + 255) / 256, 256, 0, stream>>>(x, xb);  // Ps dead
    k_cvt_w<<<(KDIM * DIM + 255) / 256, 256, 0, stream>>>(W1, WT1b);
    k_cvt_w<<<(KDIM * DIM + 255) / 256, 256, 0, stream>>>(W2, WT2b);
    k_chunk_sum<<<dim3(NCH, N_REL), 256, 0, stream>>>(cnt_in, partials);
    k_scan_partials<<<1, 256, 0, stream>>>(partials, chunk_base, row_ptr);
    k_chunk_scan<<<dim3(NCH, N_REL), 256, 0, stream>>>(cnt_in, chunk_base, row_ptr);
    k_base<<<(RN + 255) / 256, 256, 0, stream>>>(Pd, row_ptr);
    k_scatter4<<<gridH, 256, 0, stream>>>(src, dst, ew, Pd, pk_s);
    k_coef<<<dim3((N_EDGE + 255) / 256, N_REL), 256, 0, stream>>>(pk_s, rinv_out);

    const int spmm_grid = HALF_N / 4;          // 12500, exact
    const int gemm_grid = (HALF_N + 63) / 64;  // 782

    // layer 1: xb (bf16) -> h_mid_b (bf16), two halves through Tb
    for (int h = 0; h < 2; ++h) {
        k_spmm4<<<spmm_grid, 256, 0, stream>>>(row_ptr, pk_s, rinv_in,
                                               (const unsigned*)xb, (unsigned*)Tb, h * HALF_N);
        k_gemm<<<gemm_grid, 256, 0, stream>>>(Tb, WT1b, b1, (float*)nullptr, h_mid_b, h * HALF_N);
    }
    // layer 2: h_mid_b (bf16) -> out (fp32)
    for (int h = 0; h < 2; ++h) {
        k_spmm4<<<spmm_grid, 256, 0, stream>>>(row_ptr, pk_s, rinv_in,
                                               (const unsigned*)h_mid_b, (unsigned*)Tb, h * HALF_N);
        k_gemm<<<gemm_grid, 256, 0, stream>>>(Tb, WT2b, b2, out, (unsigned short*)nullptr, h * HALF_N);
    }
}

// Round 7
// 1374.779 us; speedup vs baseline: 2.6648x; 1.0310x over previous
//
#include <hip/hip_runtime.h>
#include <hip/hip_bf16.h>
#include <cstdint>
#include <cstddef>

// Problem constants
#define N_NODE 100000
#define N_EDGE 1600000
#define N_REL  4
#define DIM    128
#define KDIM   512                               // N_REL * DIM stacked
#define HALF_N 50000
#define CHUNK  2048
#define NCH    ((N_NODE + CHUNK - 1) / CHUNK)   // 49

// Histogram/scatter tiling: packed u16 counters -> TS=25000 in 50KB LDS,
// 4 passes (was 13). 512-thread blocks, 3 blocks/CU LDS cap.
#define CH_E   50000                             // edges per chunk (div by 4)
#define NCHUNK 32                                // chunks (Pd table caps this)
#define TS     25000                             // node-tile size (even)
#define NTILE  4                                 // ceil(100000/25000)

typedef __attribute__((ext_vector_type(8))) short bf16x8;   // 8 bf16 (4 VGPRs)
typedef __attribute__((ext_vector_type(4))) float f32x4;    // 4 fp32 acc

__device__ inline unsigned short f2bf(float f) {
    __hip_bfloat16 b = __float2bfloat16(f);
    return *reinterpret_cast<unsigned short*>(&b);
}

// ---------------------------------------------------------------------------
// 1) Tiled LDS histogram, packed u16 fields (count <= 50000 < 2^16).
// ---------------------------------------------------------------------------
__global__ __launch_bounds__(512) void k_hist(const int* __restrict__ idx,
                                              int* __restrict__ P) {
    __shared__ unsigned hist[TS / 2];            // 50 KB
    int c = blockIdx.x, t = blockIdx.y, r = blockIdx.z;
    for (int i = threadIdx.x; i < TS / 2; i += 512) hist[i] = 0;
    __syncthreads();
    int n0 = t * TS;
    int e0 = c * CH_E;
    const int* ip = idx + (size_t)r * N_EDGE;
    for (int e = e0 + threadIdx.x * 4; e < e0 + CH_E; e += 2048) {
        int4 d4 = *(const int4*)(ip + e);
        unsigned a0 = (unsigned)(d4.x - n0), a1 = (unsigned)(d4.y - n0);
        unsigned a2 = (unsigned)(d4.z - n0), a3 = (unsigned)(d4.w - n0);
        if (a0 < TS) atomicAdd(&hist[a0 >> 1], 1u << (16 * (a0 & 1)));
        if (a1 < TS) atomicAdd(&hist[a1 >> 1], 1u << (16 * (a1 & 1)));
        if (a2 < TS) atomicAdd(&hist[a2 >> 1], 1u << (16 * (a2 & 1)));
        if (a3 < TS) atomicAdd(&hist[a3 >> 1], 1u << (16 * (a3 & 1)));
    }
    __syncthreads();
    int* Pp = P + ((size_t)r * NCHUNK + c) * N_NODE;
    for (int i = threadIdx.x; i < TS; i += 512) {
        int n = n0 + i;
        if (n < N_NODE)
            Pp[n] = (int)((hist[i >> 1] >> (16 * (i & 1))) & 0xffffu);
    }
}

// 2) Reduce partials over chunks -> cnt_in (for scan) + rinv_in/out
__global__ void k_reduce_rinv(const int* __restrict__ Pd, const int* __restrict__ Ps,
                              int* __restrict__ cnt_in, float* __restrict__ rinv_in,
                              float* __restrict__ rinv_out) {
    int i = blockIdx.x * blockDim.x + threadIdx.x;   // r*N + n
    if (i >= N_REL * N_NODE) return;
    int r = i / N_NODE, n = i - r * N_NODE;
    int ci = 0, co = 0;
#pragma unroll
    for (int c = 0; c < NCHUNK; ++c) {
        ci += Pd[((size_t)r * NCHUNK + c) * N_NODE + n];
        co += Ps[((size_t)r * NCHUNK + c) * N_NODE + n];
    }
    cnt_in[i]   = ci;
    rinv_in[i]  = rsqrtf((float)max(ci, 1));
    rinv_out[i] = rsqrtf((float)max(co, 1));
}

// ---------------------------------------------------------------------------
// 3) CSR-by-dst row_ptr: chunk sums -> scan partials -> chunk scan
// ---------------------------------------------------------------------------
__global__ void k_chunk_sum(const int* __restrict__ cnt_in, int* __restrict__ partials) {
    int r = blockIdx.y, ch = blockIdx.x;
    __shared__ int sdata[256];
    int s = 0;
    for (int i = 0; i < CHUNK / 256; ++i) {
        int n = ch * CHUNK + i * 256 + threadIdx.x;
        if (n < N_NODE) s += cnt_in[r * N_NODE + n];
    }
    sdata[threadIdx.x] = s;
    __syncthreads();
    for (int off = 128; off > 0; off >>= 1) {
        if (threadIdx.x < off) sdata[threadIdx.x] += sdata[threadIdx.x + off];
        __syncthreads();
    }
    if (threadIdx.x == 0) partials[r * NCH + ch] = sdata[0];
}

__global__ void k_scan_partials(const int* __restrict__ partials,
                                int* __restrict__ chunk_base, int* __restrict__ row_ptr) {
    __shared__ int sp[N_REL * NCH];
    int t = threadIdx.x;
    if (t < N_REL * NCH) sp[t] = partials[t];
    __syncthreads();
    if (t == 0) {
        for (int r = 0; r < N_REL; ++r) {
            int run = 0;
            for (int ch = 0; ch < NCH; ++ch) {
                chunk_base[r * NCH + ch] = run;
                run += sp[r * NCH + ch];
            }
            row_ptr[r * (N_NODE + 1) + N_NODE] = N_EDGE;
        }
    }
}

__global__ void k_chunk_scan(const int* __restrict__ cnt_in,
                             const int* __restrict__ chunk_base, int* __restrict__ row_ptr) {
    int r = blockIdx.y, ch = blockIdx.x;
    __shared__ int tsum[256];
    int base_n = ch * CHUNK;
    int vals[8];
    int loc = 0;
    for (int i = 0; i < 8; ++i) {
        int n = base_n + threadIdx.x * 8 + i;
        vals[i] = (n < N_NODE) ? cnt_in[r * N_NODE + n] : 0;
        loc += vals[i];
    }
    tsum[threadIdx.x] = loc;
    __syncthreads();
    for (int off = 1; off < 256; off <<= 1) {     // Hillis-Steele inclusive scan
        int y = (threadIdx.x >= off) ? tsum[threadIdx.x - off] : 0;
        __syncthreads();
        tsum[threadIdx.x] += y;
        __syncthreads();
    }
    int pos = chunk_base[r * NCH + ch] + tsum[threadIdx.x] - loc;  // exclusive
    for (int i = 0; i < 8; ++i) {
        int n = base_n + threadIdx.x * 8 + i;
        if (n < N_NODE) { row_ptr[r * (N_NODE + 1) + n] = pos; pos += vals[i]; }
    }
}

// 4) In-place: P[r][c][n] := row_ptr[r][n] + sum_{c'<c} P[r][c'][n]
__global__ void k_base(int* __restrict__ P, const int* __restrict__ row_ptr) {
    int i = blockIdx.x * blockDim.x + threadIdx.x;
    if (i >= N_REL * N_NODE) return;
    int r = i / N_NODE, n = i - r * N_NODE;
    int run = row_ptr[r * (N_NODE + 1) + n];
#pragma unroll
    for (int c = 0; c < NCHUNK; ++c) {
        size_t o = ((size_t)r * NCHUNK + c) * N_NODE + n;
        int p = P[o];
        P[o] = run;
        run += p;
    }
}

// 5) Scatter: packed u16 LOCAL cursors (init 0), CSR base added per-hit via
//    L2-resident 64KB-window gather; rinv_out folded in (k_coef eliminated).
__global__ __launch_bounds__(512) void k_scatter5(const int* __restrict__ src,
                          const int* __restrict__ dst, const float* __restrict__ ew,
                          const int* __restrict__ base, const float* __restrict__ rinv_out,
                          int2* __restrict__ pk_s) {
    __shared__ unsigned cur[TS / 2];             // 50 KB, local ranks
    int c = blockIdx.x, t = blockIdx.y, r = blockIdx.z;
    for (int i = threadIdx.x; i < TS / 2; i += 512) cur[i] = 0;
    __syncthreads();
    int n0 = t * TS;
    int e0 = c * CH_E;
    const int*   bp = base + ((size_t)r * NCHUNK + c) * N_NODE + n0;
    const float* ro = rinv_out + (size_t)r * N_NODE;
    size_t roff = (size_t)r * N_EDGE;
    for (int e = e0 + threadIdx.x * 4; e < e0 + CH_E; e += 2048) {
        int4   d4 = *(const int4*)  (dst + roff + e);
        int4   s4 = *(const int4*)  (src + roff + e);
        float4 w4 = *(const float4*)(ew  + roff + e);
        unsigned a; unsigned old; int rank;
        a = (unsigned)(d4.x - n0);
        if (a < TS) {
            old = atomicAdd(&cur[a >> 1], 1u << (16 * (a & 1)));
            rank = (int)((old >> (16 * (a & 1))) & 0xffffu);
            pk_s[roff + bp[a] + rank] = make_int2(s4.x, __float_as_int(w4.x * ro[s4.x]));
        }
        a = (unsigned)(d4.y - n0);
        if (a < TS) {
            old = atomicAdd(&cur[a >> 1], 1u << (16 * (a & 1)));
            rank = (int)((old >> (16 * (a & 1))) & 0xffffu);
            pk_s[roff + bp[a] + rank] = make_int2(s4.y, __float_as_int(w4.y * ro[s4.y]));
        }
        a = (unsigned)(d4.z - n0);
        if (a < TS) {
            old = atomicAdd(&cur[a >> 1], 1u << (16 * (a & 1)));
            rank = (int)((old >> (16 * (a & 1))) & 0xffffu);
            pk_s[roff + bp[a] + rank] = make_int2(s4.z, __float_as_int(w4.z * ro[s4.z]));
        }
        a = (unsigned)(d4.w - n0);
        if (a < TS) {
            old = atomicAdd(&cur[a >> 1], 1u << (16 * (a & 1)));
            rank = (int)((old >> (16 * (a & 1))) & 0xffffu);
            pk_s[roff + bp[a] + rank] = make_int2(s4.w, __float_as_int(w4.w * ro[s4.w]));
        }
    }
}

// 7a) fp32 -> bf16 matrix convert (4 elems/thread)
__global__ void k_cvt(const float* __restrict__ x, unsigned short* __restrict__ xb) {
    int i = blockIdx.x * blockDim.x + threadIdx.x;
    if (i >= N_NODE * DIM / 4) return;
    float4 v = ((const float4*)x)[i];
    ushort4 o;
    o.x = f2bf(v.x); o.y = f2bf(v.y); o.z = f2bf(v.z); o.w = f2bf(v.w);
    ((ushort4*)xb)[i] = o;
}

// 7b) W [512][128] fp32 -> WT [128][512] bf16 (transpose for B-frag loads)
__global__ void k_cvt_w(const float* __restrict__ W, unsigned short* __restrict__ WT) {
    int i = blockIdx.x * blockDim.x + threadIdx.x;
    if (i >= KDIM * DIM) return;
    int k = i >> 7, j = i & 127;
    WT[(size_t)j * KDIM + k] = f2bf(W[i]);
}

// ---------------------------------------------------------------------------
// 8) Fused SpMM: one wave per (node, relation); 8-deep gather pipeline.
//    Block = 1 node x 4 relation-waves; lane owns dword `lane` of 256B row.
// ---------------------------------------------------------------------------
__global__ __launch_bounds__(256) void k_spmm4(const int* __restrict__ row_ptr,
                        const int2* __restrict__ pk_s,
                        const float* __restrict__ rinv_in, const unsigned* __restrict__ hb,
                        unsigned* __restrict__ Tb, int node0) {
    int r    = threadIdx.x >> 6;          // wave index = relation
    int lane = threadIdx.x & 63;
    int nl   = blockIdx.x;                // local row within half
    int node = node0 + nl;
    int k0 = row_ptr[r * (N_NODE + 1) + node];
    int k1 = row_ptr[r * (N_NODE + 1) + node + 1];
    const int2* pp = pk_s + (size_t)r * N_EDGE;
    float2 acc = make_float2(0.f, 0.f);
    int k = k0;
    for (; k + 7 < k1; k += 8) {
        int2 p0 = pp[k],     p1 = pp[k + 1], p2 = pp[k + 2], p3 = pp[k + 3];
        int2 p4 = pp[k + 4], p5 = pp[k + 5], p6 = pp[k + 6], p7 = pp[k + 7];
        unsigned u0 = hb[(size_t)p0.x * 64 + lane];
        unsigned u1 = hb[(size_t)p1.x * 64 + lane];
        unsigned u2 = hb[(size_t)p2.x * 64 + lane];
        unsigned u3 = hb[(size_t)p3.x * 64 + lane];
        unsigned u4 = hb[(size_t)p4.x * 64 + lane];
        unsigned u5 = hb[(size_t)p5.x * 64 + lane];
        unsigned u6 = hb[(size_t)p6.x * 64 + lane];
        unsigned u7 = hb[(size_t)p7.x * 64 + lane];
        float c0 = __int_as_float(p0.y), c1 = __int_as_float(p1.y);
        float c2 = __int_as_float(p2.y), c3 = __int_as_float(p3.y);
        float c4 = __int_as_float(p4.y), c5 = __int_as_float(p5.y);
        float c6 = __int_as_float(p6.y), c7 = __int_as_float(p7.y);
        acc.x += c0 * __uint_as_float(u0 << 16);
        acc.y += c0 * __uint_as_float(u0 & 0xffff0000u);
        acc.x += c1 * __uint_as_float(u1 << 16);
        acc.y += c1 * __uint_as_float(u1 & 0xffff0000u);
        acc.x += c2 * __uint_as_float(u2 << 16);
        acc.y += c2 * __uint_as_float(u2 & 0xffff0000u);
        acc.x += c3 * __uint_as_float(u3 << 16);
        acc.y += c3 * __uint_as_float(u3 & 0xffff0000u);
        acc.x += c4 * __uint_as_float(u4 << 16);
        acc.y += c4 * __uint_as_float(u4 & 0xffff0000u);
        acc.x += c5 * __uint_as_float(u5 << 16);
        acc.y += c5 * __uint_as_float(u5 & 0xffff0000u);
        acc.x += c6 * __uint_as_float(u6 << 16);
        acc.y += c6 * __uint_as_float(u6 & 0xffff0000u);
        acc.x += c7 * __uint_as_float(u7 << 16);
        acc.y += c7 * __uint_as_float(u7 & 0xffff0000u);
    }
    for (; k < k1; ++k) {
        int2 p0 = pp[k];
        unsigned u0 = hb[(size_t)p0.x * 64 + lane];
        float c0 = __int_as_float(p0.y);
        acc.x += c0 * __uint_as_float(u0 << 16);
        acc.y += c0 * __uint_as_float(u0 & 0xffff0000u);
    }
    float ri = rinv_in[r * N_NODE + node];
    acc.x *= ri; acc.y *= ri;
    Tb[(size_t)nl * 256 + r * 64 + lane] =
        ((unsigned)f2bf(acc.y) << 16) | (unsigned)f2bf(acc.x);
}

// ---------------------------------------------------------------------------
// 9) MFMA GEMM: out[HALF_N,128] = relu(T[HALF_N,512] @ Wcat[512,128] + bias_sum)
//    mfma_f32_16x16x32_bf16; verified frag layouts (A: m=lane&15,k=(lane>>4)*8+j;
//    C/D: col=lane&15, row=(lane>>4)*4+reg). WT (128KB) L2-resident, no LDS.
// ---------------------------------------------------------------------------
__global__ __launch_bounds__(256) void k_gemm(const unsigned short* __restrict__ Tb,
                                              const unsigned short* __restrict__ WT,
                                              const float* __restrict__ b,
                                              float* __restrict__ outf,
                                              unsigned short* __restrict__ outb,
                                              int node0) {
    int lane = threadIdx.x & 63;
    int wv   = threadIdx.x >> 6;
    int row0 = blockIdx.x * 64 + wv * 16;
    if (row0 >= HALF_N) return;            // HALF_N % 16 == 0: full-or-empty
    int m  = lane & 15;
    int kg = lane >> 4;

    f32x4 acc[8];
#pragma unroll
    for (int t = 0; t < 8; ++t) acc[t] = (f32x4){0.f, 0.f, 0.f, 0.f};

    const unsigned short* arow = Tb + (size_t)(row0 + m) * KDIM + kg * 8;
    for (int k0 = 0; k0 < KDIM; k0 += 32) {
        bf16x8 af = *(const bf16x8*)(arow + k0);
#pragma unroll
        for (int t = 0; t < 8; ++t) {
            bf16x8 bf = *(const bf16x8*)(WT + (size_t)(t * 16 + m) * KDIM + k0 + kg * 8);
            acc[t] = __builtin_amdgcn_mfma_f32_16x16x32_bf16(af, bf, acc[t], 0, 0, 0);
        }
    }

    int rbase = row0 + kg * 4;
#pragma unroll
    for (int t = 0; t < 8; ++t) {
        int col = t * 16 + m;
        float bs = b[col] + b[DIM + col] + b[2 * DIM + col] + b[3 * DIM + col];
#pragma unroll
        for (int rg = 0; rg < 4; ++rg) {
            float v = acc[t][rg] + bs;
            v = v > 0.f ? v : 0.f;         // relu in BOTH layers per reference
            size_t o = (size_t)(node0 + rbase + rg) * DIM + col;
            if (outb) outb[o] = f2bf(v);
            else      outf[o] = v;
        }
    }
}

// ---------------------------------------------------------------------------
extern "C" void kernel_launch(void* const* d_in, const int* in_sizes, int n_in,
                              void* d_out, int out_size, void* d_ws, size_t ws_size,
                              hipStream_t stream) {
    const float* x   = (const float*)d_in[0];
    const int*   src = (const int*)  d_in[1];
    const int*   dst = (const int*)  d_in[2];
    const float* ew  = (const float*)d_in[3];
    const float* W1  = (const float*)d_in[4];
    const float* b1  = (const float*)d_in[5];
    const float* W2  = (const float*)d_in[6];
    const float* b2  = (const float*)d_in[7];
    float* out = (float*)d_out;

    // Workspace carve-up (~162 MB, same proven footprint).
    char* p = (char*)d_ws;
    auto alloc = [&](size_t bytes) -> char* {
        char* q = p;
        p += (bytes + 255) & ~(size_t)255;
        return q;
    };
    const size_t RN = (size_t)N_REL * N_NODE;
    int*   cnt_in     = (int*)  alloc(RN * 4);
    float* rinv_out   = (float*)alloc(RN * 4);
    float* rinv_in    = (float*)alloc(RN * 4);
    int*   row_ptr    = (int*)  alloc((size_t)N_REL * (N_NODE + 1) * 4);
    int*   partials   = (int*)  alloc(N_REL * NCH * 4);
    int*   chunk_base = (int*)  alloc(N_REL * NCH * 4);
    unsigned short* WT1b = (unsigned short*)alloc((size_t)KDIM * DIM * 2);  // 128KB
    unsigned short* WT2b = (unsigned short*)alloc((size_t)KDIM * DIM * 2);  // 128KB
    int2*  pk_s       = (int2*) alloc((size_t)N_REL * N_EDGE * 8);          // 51.2 MB
    char*  Treg       =         alloc((size_t)HALF_N * KDIM * 2);           // 51.2 MB
    char*  hreg       =         alloc((size_t)N_REL * NCHUNK * N_NODE * 4); // 51.2 MB

    // Aliases:
    // Pd (dst partials -> CSR bases) in Treg: dead after k_scatter5, before spmm.
    // Ps (src partials) in hreg: dead after k_reduce_rinv; then hreg splits:
    //   [0, 25.6MB)   h_mid_b : bf16 layer-1 output
    //   [25.6, 51.2)  xb      : bf16 copy of x
    int* Pd = (int*)Treg;
    int* Ps = (int*)hreg;
    unsigned short* h_mid_b = (unsigned short*)hreg;
    unsigned short* xb      = (unsigned short*)(hreg + (size_t)N_NODE * DIM * 2);
    unsigned short* Tb      = (unsigned short*)Treg;

    dim3 gridH(NCHUNK, NTILE, N_REL);   // 32 x 4 x 4 = 512 blocks of 512 thr
    k_hist<<<gridH, 512, 0, stream>>>(dst, Pd);
    k_hist<<<gridH, 512, 0, stream>>>(src, Ps);
    k_reduce_rinv<<<((int)RN + 255) / 256, 256, 0, stream>>>(Pd, Ps, cnt_in, rinv_in, rinv_out);
    k_cvt<<<(N_NODE * DIM / 4 + 255) / 256, 256, 0, stream>>>(x, xb);  // Ps dead
    k_cvt_w<<<(KDIM * DIM + 255) / 256, 256, 0, stream>>>(W1, WT1b);
    k_cvt_w<<<(KDIM * DIM + 255) / 256, 256, 0, stream>>>(W2, WT2b);
    k_chunk_sum<<<dim3(NCH, N_REL), 256, 0, stream>>>(cnt_in, partials);
    k_scan_partials<<<1, 256, 0, stream>>>(partials, chunk_base, row_ptr);
    k_chunk_scan<<<dim3(NCH, N_REL), 256, 0, stream>>>(cnt_in, chunk_base, row_ptr);
    k_base<<<((int)RN + 255) / 256, 256, 0, stream>>>(Pd, row_ptr);
    k_scatter5<<<gridH, 512, 0, stream>>>(src, dst, ew, Pd, rinv_out, pk_s);

    const int spmm_grid = HALF_N;              // one node per block, 4 r-waves
    const int gemm_grid = (HALF_N + 63) / 64;  // 782

    // layer 1: xb (bf16) -> h_mid_b (bf16), two halves through Tb
    for (int h = 0; h < 2; ++h) {
        k_spmm4<<<spmm_grid, 256, 0, stream>>>(row_ptr, pk_s, rinv_in,
                                               (const unsigned*)xb, (unsigned*)Tb, h * HALF_N);
        k_gemm<<<gemm_grid, 256, 0, stream>>>(Tb, WT1b, b1, (float*)nullptr, h_mid_b, h * HALF_N);
    }
    // layer 2: h_mid_b (bf16) -> out (fp32)
    for (int h = 0; h < 2; ++h) {
        k_spmm4<<<spmm_grid, 256, 0, stream>>>(row_ptr, pk_s, rinv_in,
                                               (const unsigned*)h_mid_b, (unsigned*)Tb, h * HALF_N);
        k_gemm<<<gemm_grid, 256, 0, stream>>>(Tb, WT2b, b2, out, (unsigned short*)nullptr, h * HALF_N);
    }
}